// Round 12
// baseline (170.763 us; speedup 1.0000x reference)
//
#include <hip/hip_runtime.h>
#include <hip/hip_bf16.h>

// MoE FFN: B=2,T=1024,D=1024, E=32,H=256,TOPK=4, S=2,HS=1024. N=2048 tokens.
// Round 12: (1) router = 4 tokens/block (16.5KB LDS) so cvt blocks in the same
// kernel reach the 8-blocks/CU wave limit (r8-level streaming) with the router
// overlapped. (2) routed_gu = 128x128 tiles @ 512thr/8 waves (shared_down's
// proven wave layout on gathered rows); 128-granularity work-list.
// Everything else identical to r11 (which passed at 169 us).

#define N_TOK 2048
#define DDIM 1024
#define NEXP 32
#define HDIM 256
#define TOPK 4
#define NSH 2
#define HSH 1024
#define CNTS 32
#define WMAX 160
#define WM2  96

typedef unsigned short us4 __attribute__((ext_vector_type(4)));
typedef unsigned short us8 __attribute__((ext_vector_type(8)));
typedef short bf16x8 __attribute__((ext_vector_type(8)));
typedef float f32x4 __attribute__((ext_vector_type(4)));

__device__ __forceinline__ unsigned short f2bf(float f) {
  union { float f; unsigned u; } v; v.f = f;
  unsigned r = v.u + 0x7fffu + ((v.u >> 16) & 1u);   // RNE
  return (unsigned short)(r >> 16);
}
__device__ __forceinline__ float bf2f(unsigned short h) {
  union { unsigned u; float f; } v; v.u = ((unsigned)h) << 16; return v.f;
}
// packed conversion: compiler emits v_cvt_pk_bf16_f32
__device__ __forceinline__ uint2 cvt4u(float4 v) {
  union { __hip_bfloat162 b; unsigned u; } a, b2;
  a.b  = __float22bfloat162_rn(make_float2(v.x, v.y));
  b2.b = __float22bfloat162_rn(make_float2(v.z, v.w));
  return make_uint2(a.u, b2.u);
}

__device__ __forceinline__ void pipe_barrier() {
  asm volatile("s_waitcnt lgkmcnt(0)" ::: "memory");
  __builtin_amdgcn_s_barrier();
  __builtin_amdgcn_sched_barrier(0);   // pin ds_reads BELOW the barrier
}

// ---------------- prep: router (blocks 0..511, 4 tok/block) + flat cvt ----------------
// segment ends in float4 units (all divisible by 512)
#define C_X4   524288L
#define C_WG4  2621440L
#define C_WU4  4718592L
#define C_WD4  6815744L
#define C_SG4  7340032L
#define C_SU4  7864320L
#define C_TOT4 8388608L
#define NRTR   512
#define NCVT   16384

__global__ __launch_bounds__(256) void k_prep(const float* __restrict__ x,
                                              const float* __restrict__ Wr,
                                              const float* __restrict__ rb,
                                              const float* __restrict__ Wg,
                                              const float* __restrict__ Wu,
                                              const float* __restrict__ Wd,
                                              const float* __restrict__ Sg,
                                              const float* __restrict__ Su,
                                              const float* __restrict__ Sd,
                                              unsigned short* __restrict__ xb,
                                              unsigned short* __restrict__ Wgb,
                                              unsigned short* __restrict__ Wub,
                                              unsigned short* __restrict__ Wdb,
                                              unsigned short* __restrict__ Sgb,
                                              unsigned short* __restrict__ Sub,
                                              unsigned short* __restrict__ Sdb,
                                              int* __restrict__ cnt,
                                              int* __restrict__ ent,
                                              float* __restrict__ wgt) {
  __shared__ float sX[4 * 1024];
  __shared__ float sLog[4 * 32];
  int tid = threadIdx.x;
  if (blockIdx.x >= NRTR) {
    // ---- cvt: block -> contiguous 512-float4 chunk, dispatch order = HBM sweep
    long base = (long)(blockIdx.x - NRTR) * 512;
    const float* s; unsigned short* d; long off;
    if (base < C_WG4) {
      if (base < C_X4)  { s = x;  d = xb;  off = base; }
      else              { s = Wg; d = Wgb; off = base - C_X4; }
    } else if (base < C_WD4) {
      if (base < C_WU4) { s = Wu; d = Wub; off = base - C_WG4; }
      else              { s = Wd; d = Wdb; off = base - C_WU4; }
    } else if (base < C_SU4) {
      if (base < C_SG4) { s = Sg; d = Sgb; off = base - C_WD4; }
      else              { s = Su; d = Sub; off = base - C_SG4; }
    } else              { s = Sd; d = Sdb; off = base - C_SU4; }
    long i0 = off + tid;
    long i1 = i0 + 256;
    float4 v0 = reinterpret_cast<const float4*>(s)[i0];
    float4 v1 = reinterpret_cast<const float4*>(s)[i1];
    reinterpret_cast<uint2*>(d)[i0] = cvt4u(v0);
    reinterpret_cast<uint2*>(d)[i1] = cvt4u(v1);
    return;
  }
  // ---- router path: stage 4 x-rows (16KB) in LDS, threads 0..127 = (tok,e) dots
  int blk = blockIdx.x;
  {
    const float4* xsrc = reinterpret_cast<const float4*>(x + (size_t)blk * 4 * 1024);
    float4* xdst = reinterpret_cast<float4*>(sX);
#pragma unroll
    for (int i = 0; i < 4; i++) xdst[tid + 256 * i] = xsrc[tid + 256 * i];
  }
  __syncthreads();
  if (tid < 128) {
    int tloc = tid >> 5, e = tid & 31;
    const float4* wr4 = reinterpret_cast<const float4*>(Wr + (size_t)e * DDIM);
    const float* xr = sX + tloc * 1024;
    float acc = 0.f;
#pragma unroll 8
    for (int d4 = 0; d4 < 256; d4++) {
      float4 wv = wr4[d4];
      acc += xr[d4 * 4 + 0] * wv.x + xr[d4 * 4 + 1] * wv.y +
             xr[d4 * 4 + 2] * wv.z + xr[d4 * 4 + 3] * wv.w;
    }
    sLog[tloc * 32 + e] = acc;
  }
  __syncthreads();
  if (tid < 4) {
    int tok = blk * 4 + tid;
    const float* lg = sLog + tid * 32;
    int usedmask = 0;
    int idx[TOPK]; float lv[TOPK];
#pragma unroll
    for (int k = 0; k < TOPK; k++) {
      float best = -3.4e38f; int bi = 0;
      for (int ee = 0; ee < NEXP; ee++) {
        if ((usedmask >> ee) & 1) continue;
        float v = lg[ee] + rb[ee];
        if (v > best) { best = v; bi = ee; }
      }
      usedmask |= 1 << bi; idx[k] = bi; lv[k] = lg[bi];
    }
    float m = fmaxf(fmaxf(lv[0], lv[1]), fmaxf(lv[2], lv[3]));
    float w[TOPK]; float ssum = 0.f;
#pragma unroll
    for (int k = 0; k < TOPK; k++) { w[k] = __expf(lv[k] - m); ssum += w[k]; }
    float inv = 1.f / ssum;
#pragma unroll
    for (int k = 0; k < TOPK; k++) {
      int ee = idx[k];
      int pos = atomicAdd(&cnt[ee * CNTS], 1);
      ent[ee * N_TOK + pos] = tok * TOPK + k;
      wgt[ee * N_TOK + pos] = w[k] * inv;
    }
  }
}

// ---------------- work-list builder: 64- and 128-granularity ----------------
__global__ void k_plan(const int* __restrict__ cnt, int* __restrict__ wk, int* __restrict__ nwk,
                       int* __restrict__ wk2, int* __restrict__ nwk2) {
  if (threadIdx.x != 0) return;
  int w = 0, w2 = 0;
  for (int e = 0; e < NEXP; e++) {
    int ne = cnt[e * CNTS];
    int nt = (ne + 63) >> 6;
    for (int t = 0; t < nt; t++) wk[w++] = e | (t << 8);
    int nt2 = (ne + 127) >> 7;
    for (int t = 0; t < nt2; t++) wk2[w2++] = e | (t << 8);
  }
  nwk[0] = w;
  nwk2[0] = w2;
}

// ---------------- routed gate+up (+swiglu) ----------------
// grid (WM2, ht=4), 512 thr, 8 waves (2M x 4N). tile 128 gathered rows x 128
// cols (64 g | 64 u interleaved at 16; wave = 64 rows x 32 cols = 16 h g/u pairs).
__global__ __launch_bounds__(512) void k_routed_gu(const unsigned short* __restrict__ xb,
                                                   const unsigned short* __restrict__ Wgb,
                                                   const unsigned short* __restrict__ Wub,
                                                   const int* __restrict__ cnt,
                                                   const int* __restrict__ ent,
                                                   const float* __restrict__ wgt,
                                                   unsigned short* __restrict__ hw,
                                                   const int* __restrict__ wk2,
                                                   const int* __restrict__ nwk2) {
  int widx = blockIdx.x;
  if (widx >= nwk2[0]) return;
  int item = wk2[widx];
  int e = item & 255, mt = item >> 8, ht = blockIdx.y;
  int ne = cnt[e * CNTS];
  __shared__ unsigned short sA[2][128 * 40];
  __shared__ unsigned short sB[2][128 * 40];
  __shared__ int sTok[128];
  __shared__ float sW[128];
  int tid = threadIdx.x, lane = tid & 63, wid = tid >> 6;
  int wm = wid >> 2, wn = wid & 3;
  if (tid < 128) {
    int pos = mt * 128 + tid;
    int p2 = min(pos, ne - 1);
    sTok[tid] = ent[e * N_TOK + p2];
    sW[tid] = (pos < ne) ? wgt[e * N_TOK + p2] : 0.f;
  }
  __syncthreads();

  int ar = tid >> 2, akc = tid & 3;
  const unsigned short* aSrc = xb + (size_t)(sTok[ar] >> 2) * DDIM + akc * 8;
  int aOff = ar * 40 + akc * 8;
  int br = tid >> 2, bkc = tid & 3;
  int sel = (br >> 4) & 1;
  int h = ht * 64 + ((br >> 5) << 4) + (br & 15);
  const unsigned short* bSrc = (sel ? Wub : Wgb) + (size_t)(e * HDIM + h) * DDIM + bkc * 8;
  int bOff = br * 40 + bkc * 8;

  us8 aReg = *reinterpret_cast<const us8*>(aSrc);
  us8 bReg = *reinterpret_cast<const us8*>(bSrc);

  f32x4 acc[4][2];
#pragma unroll
  for (int mf = 0; mf < 4; mf++)
#pragma unroll
    for (int nf = 0; nf < 2; nf++) acc[mf][nf] = {0.f, 0.f, 0.f, 0.f};

  int cur = 0;
  for (int step = 0; step < 32; ++step) {
    *reinterpret_cast<us8*>(&sA[cur][aOff]) = aReg;
    *reinterpret_cast<us8*>(&sB[cur][bOff]) = bReg;
    if (step < 31) {
      int k0 = (step + 1) * 32;
      aReg = *reinterpret_cast<const us8*>(aSrc + k0);
      bReg = *reinterpret_cast<const us8*>(bSrc + k0);
    }
    pipe_barrier();
    int ka = (lane >> 4) * 8;
    bf16x8 a[4];
#pragma unroll
    for (int mf = 0; mf < 4; mf++)
      a[mf] = *reinterpret_cast<const bf16x8*>(&sA[cur][(wm * 64 + mf * 16 + (lane & 15)) * 40 + ka]);
#pragma unroll
    for (int nf = 0; nf < 2; nf++) {
      bf16x8 b = *reinterpret_cast<const bf16x8*>(&sB[cur][(wn * 32 + nf * 16 + (lane & 15)) * 40 + ka]);
#pragma unroll
      for (int mf = 0; mf < 4; mf++)
        acc[mf][nf] = __builtin_amdgcn_mfma_f32_16x16x32_bf16(a[mf], b, acc[mf][nf], 0, 0, 0);
    }
    cur ^= 1;
  }
  // wave col c = wn*32 + nf*16 + i: sel = nf (g/u), h = ht*64 + wn*16 + i
#pragma unroll
  for (int mf = 0; mf < 4; mf++) {
#pragma unroll
    for (int r = 0; r < 4; r++) {
      int tl = wm * 64 + mf * 16 + ((lane >> 4) << 2) + r;
      int pos = mt * 128 + tl;
      if (pos < ne) {
        float g = acc[mf][0][r], u = acc[mf][1][r];
        float hval = (g / (1.f + __expf(-g))) * u * sW[tl];
        int ts = sTok[tl];
        int hcol = ht * 64 + wn * 16 + (lane & 15);
        hw[(size_t)ts * HDIM + hcol] = f2bf(hval);
      }
    }
  }
}

// ---------------- routed down-proj (bf16 per-slot store) ----------------
// grid (WMAX, dh=4), 256 thr. tile 64 rows x 256 d-cols, K=256.
__global__ __launch_bounds__(256) void k_routed_down(const unsigned short* __restrict__ hw,
                                                     const unsigned short* __restrict__ Wdb,
                                                     const int* __restrict__ cnt,
                                                     const int* __restrict__ ent,
                                                     unsigned short* __restrict__ Pslot,
                                                     const int* __restrict__ wk,
                                                     const int* __restrict__ nwk) {
  int widx = blockIdx.x;
  if (widx >= nwk[0]) return;
  int item = wk[widx];
  int e = item & 255, mt = item >> 8, dh = blockIdx.y;
  int ne = cnt[e * CNTS];
  __shared__ unsigned short sA[2][64 * 40];
  __shared__ unsigned short sB[2][256 * 40];
  __shared__ int sTok[64];
  int tid = threadIdx.x, lane = tid & 63, w = tid >> 6;
  if (tid < 64) {
    int pos = mt * 64 + tid;
    int p2 = min(pos, ne - 1);
    sTok[tid] = ent[e * N_TOK + p2];
  }
  __syncthreads();

  int arow = tid >> 2, akc = tid & 3;
  const unsigned short* aSrc = hw + (size_t)sTok[arow] * HDIM + akc * 8;
  int aOff = arow * 40 + akc * 8;
  const unsigned short* bSrc[4];
  int bOff[4];
#pragma unroll
  for (int p = 0; p < 4; p++) {
    int c = tid + p * 256;
    int row = c >> 2, kc = c & 3;
    int d = dh * 256 + row;
    bSrc[p] = Wdb + (size_t)(e * DDIM + d) * HDIM + kc * 8;
    bOff[p] = row * 40 + kc * 8;
  }

  us8 aReg = *reinterpret_cast<const us8*>(aSrc);
  us8 bReg[4];
#pragma unroll
  for (int p = 0; p < 4; p++) bReg[p] = *reinterpret_cast<const us8*>(bSrc[p]);

  f32x4 acc[16];
#pragma unroll
  for (int f = 0; f < 16; f++) acc[f] = {0.f, 0.f, 0.f, 0.f};

  int cur = 0;
  for (int step = 0; step < 8; ++step) {
    *reinterpret_cast<us8*>(&sA[cur][aOff]) = aReg;
#pragma unroll
    for (int p = 0; p < 4; p++) *reinterpret_cast<us8*>(&sB[cur][bOff[p]]) = bReg[p];
    if (step < 7) {
      int k0 = (step + 1) * 32;
      aReg = *reinterpret_cast<const us8*>(aSrc + k0);
#pragma unroll
      for (int p = 0; p < 4; p++) bReg[p] = *reinterpret_cast<const us8*>(bSrc[p] + k0);
    }
    pipe_barrier();
    int ka = (lane >> 4) * 8;
    bf16x8 a = *reinterpret_cast<const bf16x8*>(&sA[cur][(w * 16 + (lane & 15)) * 40 + ka]);
#pragma unroll
    for (int f = 0; f < 16; f++) {
      bf16x8 b = *reinterpret_cast<const bf16x8*>(&sB[cur][(f * 16 + (lane & 15)) * 40 + ka]);
      acc[f] = __builtin_amdgcn_mfma_f32_16x16x32_bf16(a, b, acc[f], 0, 0, 0);
    }
    cur ^= 1;
  }
#pragma unroll
  for (int f = 0; f < 16; f++) {
#pragma unroll
    for (int r = 0; r < 4; r++) {
      int tl = w * 16 + ((lane >> 4) << 2) + r;
      int pos = mt * 64 + tl;
      if (pos < ne) {
        int ts = sTok[tl];
        int d = dh * 256 + f * 16 + (lane & 15);
        Pslot[(size_t)ts * DDIM + d] = f2bf(acc[f][r]);
      }
    }
  }
}

// ---------------- shared gate+up (+swiglu) ----------------
// grid (x = s*8+ht [16], y = mt [16]). 512 thr, 8 waves (2M x 4N).
// tile 128 rows x 256 cols (128 g | 128 u interleaved at 16), K=1024.
__global__ __launch_bounds__(512) void k_shared_gu(const unsigned short* __restrict__ xb,
                                                   const unsigned short* __restrict__ Sgb,
                                                   const unsigned short* __restrict__ Sub,
                                                   unsigned short* __restrict__ hs) {
  int s = blockIdx.x >> 3, ht = blockIdx.x & 7;
  int mt = blockIdx.y;
  __shared__ unsigned short sA[2][128 * 40];
  __shared__ unsigned short sB[2][256 * 40];
  int tid = threadIdx.x, lane = tid & 63, wid = tid >> 6;
  int wm = wid >> 2, wn = wid & 3;

  // A: 128 rows x 4 us8-chunks = 512 -> 1 chunk/thread
  int ar = tid >> 2, akc = tid & 3;
  const unsigned short* aSrc = xb + (size_t)(mt * 128 + ar) * DDIM + akc * 8;
  int aOff = ar * 40 + akc * 8;
  // B: 256 rows x 4 chunks = 1024 -> 2 chunks/thread
  const unsigned short* bSrc[2];
  int bOff[2];
#pragma unroll
  for (int p = 0; p < 2; p++) {
    int c = tid + p * 512;
    int row = c >> 2, kc = c & 3;
    int sel = (row >> 4) & 1;
    int h = ht * 128 + ((row >> 5) << 4) + (row & 15);
    bSrc[p] = (sel ? Sub : Sgb) + (size_t)(s * HSH + h) * DDIM + kc * 8;
    bOff[p] = row * 40 + kc * 8;
  }

  us8 aReg = *reinterpret_cast<const us8*>(aSrc);
  us8 bReg[2];
#pragma unroll
  for (int p = 0; p < 2; p++) bReg[p] = *reinterpret_cast<const us8*>(bSrc[p]);

  f32x4 acc[4][4];
#pragma unroll
  for (int mf = 0; mf < 4; mf++)
#pragma unroll
    for (int nf = 0; nf < 4; nf++) acc[mf][nf] = {0.f, 0.f, 0.f, 0.f};

  int cur = 0;
  for (int step = 0; step < 32; ++step) {
    *reinterpret_cast<us8*>(&sA[cur][aOff]) = aReg;
#pragma unroll
    for (int p = 0; p < 2; p++) *reinterpret_cast<us8*>(&sB[cur][bOff[p]]) = bReg[p];
    if (step < 31) {
      int k0 = (step + 1) * 32;
      aReg = *reinterpret_cast<const us8*>(aSrc + k0);
#pragma unroll
      for (int p = 0; p < 2; p++) bReg[p] = *reinterpret_cast<const us8*>(bSrc[p] + k0);
    }
    pipe_barrier();
    int ka = (lane >> 4) * 8;
    bf16x8 a[4];
#pragma unroll
    for (int mf = 0; mf < 4; mf++)
      a[mf] = *reinterpret_cast<const bf16x8*>(&sA[cur][(wm * 64 + mf * 16 + (lane & 15)) * 40 + ka]);
#pragma unroll
    for (int nf = 0; nf < 4; nf++) {
      bf16x8 b = *reinterpret_cast<const bf16x8*>(&sB[cur][(wn * 64 + nf * 16 + (lane & 15)) * 40 + ka]);
#pragma unroll
      for (int mf = 0; mf < 4; mf++)
        acc[mf][nf] = __builtin_amdgcn_mfma_f32_16x16x32_bf16(a[mf], b, acc[mf][nf], 0, 0, 0);
    }
    cur ^= 1;
  }
  // wave col c = wn*64+nf*16: sel = nf&1, h16-block = wn*2 + (nf>>1)
#pragma unroll
  for (int mf = 0; mf < 4; mf++) {
#pragma unroll
    for (int t = 0; t < 2; t++) {
#pragma unroll
      for (int r = 0; r < 4; r++) {
        int tok = mt * 128 + wm * 64 + mf * 16 + ((lane >> 4) << 2) + r;
        float g = acc[mf][2 * t][r], u = acc[mf][2 * t + 1][r];
        float hval = (g / (1.f + __expf(-g))) * u;
        int h = ht * 128 + (wn * 2 + t) * 16 + (lane & 15);
        hs[(size_t)(tok * NSH + s) * HSH + h] = f2bf(hval);
      }
    }
  }
}

// ---------------- shared down-proj (per-s bf16 partial) ----------------
// grid (x = dh*2+s [16], y = mt [16]). 512 thr, 8 waves (2M x 4N).
// tile 128 rows x 128 d-cols (wave = 64x32), K=1024.
__global__ __launch_bounds__(512) void k_shared_down(const unsigned short* __restrict__ hs,
                                                     const unsigned short* __restrict__ Sdb,
                                                     unsigned short* __restrict__ Psh) {
  int dh = blockIdx.x >> 1, s = blockIdx.x & 1;
  int mt = blockIdx.y;
  __shared__ unsigned short sA[2][128 * 40];
  __shared__ unsigned short sB[2][128 * 40];
  int tid = threadIdx.x, lane = tid & 63, wid = tid >> 6;
  int wm = wid >> 2, wn = wid & 3;

  int ar = tid >> 2, akc = tid & 3;
  const unsigned short* aSrc = hs + (size_t)((mt * 128 + ar) * NSH + s) * HSH + akc * 8;
  int aOff = ar * 40 + akc * 8;
  int br = tid >> 2, bkc = tid & 3;
  const unsigned short* bSrc = Sdb + (size_t)(s * DDIM + dh * 128 + br) * HSH + bkc * 8;
  int bOff = br * 40 + bkc * 8;

  us8 aReg = *reinterpret_cast<const us8*>(aSrc);
  us8 bReg = *reinterpret_cast<const us8*>(bSrc);

  f32x4 acc[4][2];
#pragma unroll
  for (int mf = 0; mf < 4; mf++)
#pragma unroll
    for (int nf = 0; nf < 2; nf++) acc[mf][nf] = {0.f, 0.f, 0.f, 0.f};

  int cur = 0;
  for (int step = 0; step < 32; ++step) {
    *reinterpret_cast<us8*>(&sA[cur][aOff]) = aReg;
    *reinterpret_cast<us8*>(&sB[cur][bOff]) = bReg;
    if (step < 31) {
      int k0 = (step + 1) * 32;
      aReg = *reinterpret_cast<const us8*>(aSrc + k0);
      bReg = *reinterpret_cast<const us8*>(bSrc + k0);
    }
    pipe_barrier();
    int ka = (lane >> 4) * 8;
    bf16x8 a[4];
#pragma unroll
    for (int mf = 0; mf < 4; mf++)
      a[mf] = *reinterpret_cast<const bf16x8*>(&sA[cur][(wm * 64 + mf * 16 + (lane & 15)) * 40 + ka]);
#pragma unroll
    for (int nf = 0; nf < 2; nf++) {
      bf16x8 b = *reinterpret_cast<const bf16x8*>(&sB[cur][(wn * 32 + nf * 16 + (lane & 15)) * 40 + ka]);
#pragma unroll
      for (int mf = 0; mf < 4; mf++)
        acc[mf][nf] = __builtin_amdgcn_mfma_f32_16x16x32_bf16(a[mf], b, acc[mf][nf], 0, 0, 0);
    }
    cur ^= 1;
  }
#pragma unroll
  for (int mf = 0; mf < 4; mf++) {
#pragma unroll
    for (int nf = 0; nf < 2; nf++) {
#pragma unroll
      for (int r = 0; r < 4; r++) {
        int tok = mt * 128 + wm * 64 + mf * 16 + ((lane >> 4) << 2) + r;
        int d = dh * 128 + wn * 32 + nf * 16 + (lane & 15);
        Psh[(size_t)s * N_TOK * DDIM + (size_t)tok * DDIM + d] = f2bf(acc[mf][nf][r]);
      }
    }
  }
}

// ---------------- final combine ----------------
__global__ __launch_bounds__(256) void k_combine(const unsigned short* __restrict__ Pslot,
                                                 const unsigned short* __restrict__ Psh,
                                                 float* __restrict__ out) {
  int i = blockIdx.x * 256 + threadIdx.x;
  int base = i * 8;
  int tok = base >> 10, d = base & 1023;
  const us8 p0 = *reinterpret_cast<const us8*>(Pslot + ((size_t)tok * 4 + 0) * DDIM + d);
  const us8 p1 = *reinterpret_cast<const us8*>(Pslot + ((size_t)tok * 4 + 1) * DDIM + d);
  const us8 p2 = *reinterpret_cast<const us8*>(Pslot + ((size_t)tok * 4 + 2) * DDIM + d);
  const us8 p3 = *reinterpret_cast<const us8*>(Pslot + ((size_t)tok * 4 + 3) * DDIM + d);
  const us8 q0 = *reinterpret_cast<const us8*>(Psh + (size_t)base);
  const us8 q1 = *reinterpret_cast<const us8*>(Psh + (size_t)N_TOK * DDIM + base);
  float o[8];
#pragma unroll
  for (int j = 0; j < 8; j++)
    o[j] = bf2f(p0[j]) + bf2f(p1[j]) + bf2f(p2[j]) + bf2f(p3[j]) + bf2f(q0[j]) + bf2f(q1[j]);
  float4 v0 = {o[0], o[1], o[2], o[3]};
  float4 v1 = {o[4], o[5], o[6], o[7]};
  reinterpret_cast<float4*>(out + base)[0] = v0;
  reinterpret_cast<float4*>(out + base)[1] = v1;
}

extern "C" void kernel_launch(void* const* d_in, const int* in_sizes, int n_in,
                              void* d_out, int out_size, void* d_ws, size_t ws_size,
                              hipStream_t stream) {
  const float* x  = (const float*)d_in[0];
  const float* Wr = (const float*)d_in[1];
  const float* rb = (const float*)d_in[2];
  const float* Wg = (const float*)d_in[3];
  const float* Wu = (const float*)d_in[4];
  const float* Wd = (const float*)d_in[5];
  const float* Sg = (const float*)d_in[6];
  const float* Su = (const float*)d_in[7];
  const float* Sd = (const float*)d_in[8];
  float* out = (float*)d_out;
  char* w = (char*)d_ws;

  unsigned short* xb    = (unsigned short*)(w + (size_t)0);            // 4MB
  unsigned short* Wgb   = (unsigned short*)(w + ((size_t)4  << 20));   // 16MB
  unsigned short* Wub   = (unsigned short*)(w + ((size_t)20 << 20));   // 16MB
  unsigned short* Wdb   = (unsigned short*)(w + ((size_t)36 << 20));   // 16MB
  unsigned short* Sgb   = (unsigned short*)(w + ((size_t)52 << 20));   // 4MB
  unsigned short* Sub   = (unsigned short*)(w + ((size_t)56 << 20));   // 4MB
  unsigned short* Sdb   = (unsigned short*)(w + ((size_t)60 << 20));   // 4MB
  unsigned short* hw    = (unsigned short*)(w + ((size_t)64 << 20));   // 4MB
  unsigned short* hs    = (unsigned short*)(w + ((size_t)68 << 20));   // 8MB
  unsigned short* Pslot = (unsigned short*)(w + ((size_t)76 << 20));   // 16MB
  unsigned short* Psh   = (unsigned short*)(w + ((size_t)92 << 20));   // 8MB
  int*   cnt = (int*)(w + ((size_t)100 << 20));
  int*   ent = (int*)(w + ((size_t)100 << 20) + 8192);
  float* wgt = (float*)(w + ((size_t)100 << 20) + 8192 + (size_t)NEXP * N_TOK * 4);
  int*   wk   = (int*)(w + ((size_t)102 << 20));
  int*   nwk  = (int*)(w + ((size_t)102 << 20) + 4096);
  int*   wk2  = (int*)(w + ((size_t)102 << 20) + 8192);
  int*   nwk2 = (int*)(w + ((size_t)102 << 20) + 12288);

  hipMemsetAsync(cnt, 0, NEXP * CNTS * sizeof(int), stream);

  k_prep<<<NRTR + NCVT, 256, 0, stream>>>(x, Wr, rb, Wg, Wu, Wd, Sg, Su, Sd,
                                          xb, Wgb, Wub, Wdb, Sgb, Sub, Sdb,
                                          cnt, ent, wgt);
  k_plan<<<1, 64, 0, stream>>>(cnt, wk, nwk, wk2, nwk2);

  k_routed_gu<<<dim3(WM2, 4), 512, 0, stream>>>(xb, Wgb, Wub, cnt, ent, wgt, hw, wk2, nwk2);
  k_routed_down<<<dim3(WMAX, 4), 256, 0, stream>>>(hw, Wdb, cnt, ent, Pslot, wk, nwk);

  k_shared_gu<<<dim3(16, 16), 512, 0, stream>>>(xb, Sgb, Sub, hs);
  k_shared_down<<<dim3(16, 16), 512, 0, stream>>>(hs, Sdb, Psh);

  k_combine<<<N_TOK * DDIM / (256 * 8), 256, 0, stream>>>(Pslot, Psh, out);
}

// Round 13
// 164.170 us; speedup vs baseline: 1.0402x; 1.0402x over previous
//
#include <hip/hip_runtime.h>
#include <hip/hip_bf16.h>

// MoE FFN: B=2,T=1024,D=1024, E=32,H=256,TOPK=4, S=2,HS=1024. N=2048 tokens.
// Round 13: attribution round. k_prep reverted byte-exact to r11's proven
// version (8 tok/block router, 256 blocks, 33KB LDS -> 59us measured);
// routed_gu keeps r12's 128x128 @8-wave tile. All else = r11/r12 common.

#define N_TOK 2048
#define DDIM 1024
#define NEXP 32
#define HDIM 256
#define TOPK 4
#define NSH 2
#define HSH 1024
#define CNTS 32
#define WMAX 160
#define WM2  96

typedef unsigned short us4 __attribute__((ext_vector_type(4)));
typedef unsigned short us8 __attribute__((ext_vector_type(8)));
typedef short bf16x8 __attribute__((ext_vector_type(8)));
typedef float f32x4 __attribute__((ext_vector_type(4)));

__device__ __forceinline__ unsigned short f2bf(float f) {
  union { float f; unsigned u; } v; v.f = f;
  unsigned r = v.u + 0x7fffu + ((v.u >> 16) & 1u);   // RNE
  return (unsigned short)(r >> 16);
}
__device__ __forceinline__ float bf2f(unsigned short h) {
  union { unsigned u; float f; } v; v.u = ((unsigned)h) << 16; return v.f;
}
// packed conversion: compiler emits v_cvt_pk_bf16_f32
__device__ __forceinline__ uint2 cvt4u(float4 v) {
  union { __hip_bfloat162 b; unsigned u; } a, b2;
  a.b  = __float22bfloat162_rn(make_float2(v.x, v.y));
  b2.b = __float22bfloat162_rn(make_float2(v.z, v.w));
  return make_uint2(a.u, b2.u);
}

__device__ __forceinline__ void pipe_barrier() {
  asm volatile("s_waitcnt lgkmcnt(0)" ::: "memory");
  __builtin_amdgcn_s_barrier();
  __builtin_amdgcn_sched_barrier(0);   // pin ds_reads BELOW the barrier
}

// ---------------- prep: router (blocks 0..255, LDS-staged) + flat cvt ----------------
// segment ends in float4 units (all divisible by 512)
#define C_X4   524288L
#define C_WG4  2621440L
#define C_WU4  4718592L
#define C_WD4  6815744L
#define C_SG4  7340032L
#define C_SU4  7864320L
#define C_TOT4 8388608L
#define NCVT   16384

__global__ __launch_bounds__(256) void k_prep(const float* __restrict__ x,
                                              const float* __restrict__ Wr,
                                              const float* __restrict__ rb,
                                              const float* __restrict__ Wg,
                                              const float* __restrict__ Wu,
                                              const float* __restrict__ Wd,
                                              const float* __restrict__ Sg,
                                              const float* __restrict__ Su,
                                              const float* __restrict__ Sd,
                                              unsigned short* __restrict__ xb,
                                              unsigned short* __restrict__ Wgb,
                                              unsigned short* __restrict__ Wub,
                                              unsigned short* __restrict__ Wdb,
                                              unsigned short* __restrict__ Sgb,
                                              unsigned short* __restrict__ Sub,
                                              unsigned short* __restrict__ Sdb,
                                              int* __restrict__ cnt,
                                              int* __restrict__ ent,
                                              float* __restrict__ wgt) {
  __shared__ float sX[8 * 1024];
  __shared__ float sLog[8 * 32];
  int tid = threadIdx.x;
  if (blockIdx.x >= 256) {
    // ---- cvt: block -> contiguous 512-float4 chunk, dispatch order = HBM sweep
    long base = (long)(blockIdx.x - 256) * 512;
    const float* s; unsigned short* d; long off;
    if (base < C_WG4) {
      if (base < C_X4)  { s = x;  d = xb;  off = base; }
      else              { s = Wg; d = Wgb; off = base - C_X4; }
    } else if (base < C_WD4) {
      if (base < C_WU4) { s = Wu; d = Wub; off = base - C_WG4; }
      else              { s = Wd; d = Wdb; off = base - C_WU4; }
    } else if (base < C_SU4) {
      if (base < C_SG4) { s = Sg; d = Sgb; off = base - C_WD4; }
      else              { s = Su; d = Sub; off = base - C_SG4; }
    } else              { s = Sd; d = Sdb; off = base - C_SU4; }
    long i0 = off + tid;
    long i1 = i0 + 256;
    float4 v0 = reinterpret_cast<const float4*>(s)[i0];
    float4 v1 = reinterpret_cast<const float4*>(s)[i1];
    reinterpret_cast<uint2*>(d)[i0] = cvt4u(v0);
    reinterpret_cast<uint2*>(d)[i1] = cvt4u(v1);
    return;
  }
  // ---- router path (r2-proven): stage 8 x-rows in LDS, thread = (tok, e) dot
  int blk = blockIdx.x;
  {
    const float4* xsrc = reinterpret_cast<const float4*>(x + (size_t)blk * 8 * 1024);
    float4* xdst = reinterpret_cast<float4*>(sX);
#pragma unroll
    for (int i = 0; i < 8; i++) xdst[tid + 256 * i] = xsrc[tid + 256 * i];
  }
  __syncthreads();
  int tloc = tid >> 5, e = tid & 31;
  const float4* wr4 = reinterpret_cast<const float4*>(Wr + (size_t)e * DDIM);
  const float* xr = sX + tloc * 1024;
  float acc = 0.f;
#pragma unroll 8
  for (int d4 = 0; d4 < 256; d4++) {
    float4 wv = wr4[d4];
    acc += xr[d4 * 4 + 0] * wv.x + xr[d4 * 4 + 1] * wv.y +
           xr[d4 * 4 + 2] * wv.z + xr[d4 * 4 + 3] * wv.w;
  }
  sLog[tloc * 32 + e] = acc;
  __syncthreads();
  if (tid < 8) {
    int tok = blk * 8 + tid;
    const float* lg = sLog + tid * 32;
    int usedmask = 0;
    int idx[TOPK]; float lv[TOPK];
#pragma unroll
    for (int k = 0; k < TOPK; k++) {
      float best = -3.4e38f; int bi = 0;
      for (int ee = 0; ee < NEXP; ee++) {
        if ((usedmask >> ee) & 1) continue;
        float v = lg[ee] + rb[ee];
        if (v > best) { best = v; bi = ee; }
      }
      usedmask |= 1 << bi; idx[k] = bi; lv[k] = lg[bi];
    }
    float m = fmaxf(fmaxf(lv[0], lv[1]), fmaxf(lv[2], lv[3]));
    float w[TOPK]; float ssum = 0.f;
#pragma unroll
    for (int k = 0; k < TOPK; k++) { w[k] = __expf(lv[k] - m); ssum += w[k]; }
    float inv = 1.f / ssum;
#pragma unroll
    for (int k = 0; k < TOPK; k++) {
      int ee = idx[k];
      int pos = atomicAdd(&cnt[ee * CNTS], 1);
      ent[ee * N_TOK + pos] = tok * TOPK + k;
      wgt[ee * N_TOK + pos] = w[k] * inv;
    }
  }
}

// ---------------- work-list builder: 64- and 128-granularity ----------------
__global__ void k_plan(const int* __restrict__ cnt, int* __restrict__ wk, int* __restrict__ nwk,
                       int* __restrict__ wk2, int* __restrict__ nwk2) {
  if (threadIdx.x != 0) return;
  int w = 0, w2 = 0;
  for (int e = 0; e < NEXP; e++) {
    int ne = cnt[e * CNTS];
    int nt = (ne + 63) >> 6;
    for (int t = 0; t < nt; t++) wk[w++] = e | (t << 8);
    int nt2 = (ne + 127) >> 7;
    for (int t = 0; t < nt2; t++) wk2[w2++] = e | (t << 8);
  }
  nwk[0] = w;
  nwk2[0] = w2;
}

// ---------------- routed gate+up (+swiglu) ----------------
// grid (WM2, ht=4), 512 thr, 8 waves (2M x 4N). tile 128 gathered rows x 128
// cols (64 g | 64 u interleaved at 16; wave = 64 rows x 32 cols = 16 h g/u pairs).
__global__ __launch_bounds__(512) void k_routed_gu(const unsigned short* __restrict__ xb,
                                                   const unsigned short* __restrict__ Wgb,
                                                   const unsigned short* __restrict__ Wub,
                                                   const int* __restrict__ cnt,
                                                   const int* __restrict__ ent,
                                                   const float* __restrict__ wgt,
                                                   unsigned short* __restrict__ hw,
                                                   const int* __restrict__ wk2,
                                                   const int* __restrict__ nwk2) {
  int widx = blockIdx.x;
  if (widx >= nwk2[0]) return;
  int item = wk2[widx];
  int e = item & 255, mt = item >> 8, ht = blockIdx.y;
  int ne = cnt[e * CNTS];
  __shared__ unsigned short sA[2][128 * 40];
  __shared__ unsigned short sB[2][128 * 40];
  __shared__ int sTok[128];
  __shared__ float sW[128];
  int tid = threadIdx.x, lane = tid & 63, wid = tid >> 6;
  int wm = wid >> 2, wn = wid & 3;
  if (tid < 128) {
    int pos = mt * 128 + tid;
    int p2 = min(pos, ne - 1);
    sTok[tid] = ent[e * N_TOK + p2];
    sW[tid] = (pos < ne) ? wgt[e * N_TOK + p2] : 0.f;
  }
  __syncthreads();

  int ar = tid >> 2, akc = tid & 3;
  const unsigned short* aSrc = xb + (size_t)(sTok[ar] >> 2) * DDIM + akc * 8;
  int aOff = ar * 40 + akc * 8;
  int br = tid >> 2, bkc = tid & 3;
  int sel = (br >> 4) & 1;
  int h = ht * 64 + ((br >> 5) << 4) + (br & 15);
  const unsigned short* bSrc = (sel ? Wub : Wgb) + (size_t)(e * HDIM + h) * DDIM + bkc * 8;
  int bOff = br * 40 + bkc * 8;

  us8 aReg = *reinterpret_cast<const us8*>(aSrc);
  us8 bReg = *reinterpret_cast<const us8*>(bSrc);

  f32x4 acc[4][2];
#pragma unroll
  for (int mf = 0; mf < 4; mf++)
#pragma unroll
    for (int nf = 0; nf < 2; nf++) acc[mf][nf] = {0.f, 0.f, 0.f, 0.f};

  int cur = 0;
  for (int step = 0; step < 32; ++step) {
    *reinterpret_cast<us8*>(&sA[cur][aOff]) = aReg;
    *reinterpret_cast<us8*>(&sB[cur][bOff]) = bReg;
    if (step < 31) {
      int k0 = (step + 1) * 32;
      aReg = *reinterpret_cast<const us8*>(aSrc + k0);
      bReg = *reinterpret_cast<const us8*>(bSrc + k0);
    }
    pipe_barrier();
    int ka = (lane >> 4) * 8;
    bf16x8 a[4];
#pragma unroll
    for (int mf = 0; mf < 4; mf++)
      a[mf] = *reinterpret_cast<const bf16x8*>(&sA[cur][(wm * 64 + mf * 16 + (lane & 15)) * 40 + ka]);
#pragma unroll
    for (int nf = 0; nf < 2; nf++) {
      bf16x8 b = *reinterpret_cast<const bf16x8*>(&sB[cur][(wn * 32 + nf * 16 + (lane & 15)) * 40 + ka]);
#pragma unroll
      for (int mf = 0; mf < 4; mf++)
        acc[mf][nf] = __builtin_amdgcn_mfma_f32_16x16x32_bf16(a[mf], b, acc[mf][nf], 0, 0, 0);
    }
    cur ^= 1;
  }
  // wave col c = wn*32 + nf*16 + i: sel = nf (g/u), h = ht*64 + wn*16 + i
#pragma unroll
  for (int mf = 0; mf < 4; mf++) {
#pragma unroll
    for (int r = 0; r < 4; r++) {
      int tl = wm * 64 + mf * 16 + ((lane >> 4) << 2) + r;
      int pos = mt * 128 + tl;
      if (pos < ne) {
        float g = acc[mf][0][r], u = acc[mf][1][r];
        float hval = (g / (1.f + __expf(-g))) * u * sW[tl];
        int ts = sTok[tl];
        int hcol = ht * 64 + wn * 16 + (lane & 15);
        hw[(size_t)ts * HDIM + hcol] = f2bf(hval);
      }
    }
  }
}

// ---------------- routed down-proj (bf16 per-slot store) ----------------
// grid (WMAX, dh=4), 256 thr. tile 64 rows x 256 d-cols, K=256.
__global__ __launch_bounds__(256) void k_routed_down(const unsigned short* __restrict__ hw,
                                                     const unsigned short* __restrict__ Wdb,
                                                     const int* __restrict__ cnt,
                                                     const int* __restrict__ ent,
                                                     unsigned short* __restrict__ Pslot,
                                                     const int* __restrict__ wk,
                                                     const int* __restrict__ nwk) {
  int widx = blockIdx.x;
  if (widx >= nwk[0]) return;
  int item = wk[widx];
  int e = item & 255, mt = item >> 8, dh = blockIdx.y;
  int ne = cnt[e * CNTS];
  __shared__ unsigned short sA[2][64 * 40];
  __shared__ unsigned short sB[2][256 * 40];
  __shared__ int sTok[64];
  int tid = threadIdx.x, lane = tid & 63, w = tid >> 6;
  if (tid < 64) {
    int pos = mt * 64 + tid;
    int p2 = min(pos, ne - 1);
    sTok[tid] = ent[e * N_TOK + p2];
  }
  __syncthreads();

  int arow = tid >> 2, akc = tid & 3;
  const unsigned short* aSrc = hw + (size_t)sTok[arow] * HDIM + akc * 8;
  int aOff = arow * 40 + akc * 8;
  const unsigned short* bSrc[4];
  int bOff[4];
#pragma unroll
  for (int p = 0; p < 4; p++) {
    int c = tid + p * 256;
    int row = c >> 2, kc = c & 3;
    int d = dh * 256 + row;
    bSrc[p] = Wdb + (size_t)(e * DDIM + d) * HDIM + kc * 8;
    bOff[p] = row * 40 + kc * 8;
  }

  us8 aReg = *reinterpret_cast<const us8*>(aSrc);
  us8 bReg[4];
#pragma unroll
  for (int p = 0; p < 4; p++) bReg[p] = *reinterpret_cast<const us8*>(bSrc[p]);

  f32x4 acc[16];
#pragma unroll
  for (int f = 0; f < 16; f++) acc[f] = {0.f, 0.f, 0.f, 0.f};

  int cur = 0;
  for (int step = 0; step < 8; ++step) {
    *reinterpret_cast<us8*>(&sA[cur][aOff]) = aReg;
#pragma unroll
    for (int p = 0; p < 4; p++) *reinterpret_cast<us8*>(&sB[cur][bOff[p]]) = bReg[p];
    if (step < 7) {
      int k0 = (step + 1) * 32;
      aReg = *reinterpret_cast<const us8*>(aSrc + k0);
#pragma unroll
      for (int p = 0; p < 4; p++) bReg[p] = *reinterpret_cast<const us8*>(bSrc[p] + k0);
    }
    pipe_barrier();
    int ka = (lane >> 4) * 8;
    bf16x8 a = *reinterpret_cast<const bf16x8*>(&sA[cur][(w * 16 + (lane & 15)) * 40 + ka]);
#pragma unroll
    for (int f = 0; f < 16; f++) {
      bf16x8 b = *reinterpret_cast<const bf16x8*>(&sB[cur][(f * 16 + (lane & 15)) * 40 + ka]);
      acc[f] = __builtin_amdgcn_mfma_f32_16x16x32_bf16(a, b, acc[f], 0, 0, 0);
    }
    cur ^= 1;
  }
#pragma unroll
  for (int f = 0; f < 16; f++) {
#pragma unroll
    for (int r = 0; r < 4; r++) {
      int tl = w * 16 + ((lane >> 4) << 2) + r;
      int pos = mt * 64 + tl;
      if (pos < ne) {
        int ts = sTok[tl];
        int d = dh * 256 + f * 16 + (lane & 15);
        Pslot[(size_t)ts * DDIM + d] = f2bf(acc[f][r]);
      }
    }
  }
}

// ---------------- shared gate+up (+swiglu) ----------------
// grid (x = s*8+ht [16], y = mt [16]). 512 thr, 8 waves (2M x 4N).
// tile 128 rows x 256 cols (128 g | 128 u interleaved at 16), K=1024.
__global__ __launch_bounds__(512) void k_shared_gu(const unsigned short* __restrict__ xb,
                                                   const unsigned short* __restrict__ Sgb,
                                                   const unsigned short* __restrict__ Sub,
                                                   unsigned short* __restrict__ hs) {
  int s = blockIdx.x >> 3, ht = blockIdx.x & 7;
  int mt = blockIdx.y;
  __shared__ unsigned short sA[2][128 * 40];
  __shared__ unsigned short sB[2][256 * 40];
  int tid = threadIdx.x, lane = tid & 63, wid = tid >> 6;
  int wm = wid >> 2, wn = wid & 3;

  // A: 128 rows x 4 us8-chunks = 512 -> 1 chunk/thread
  int ar = tid >> 2, akc = tid & 3;
  const unsigned short* aSrc = xb + (size_t)(mt * 128 + ar) * DDIM + akc * 8;
  int aOff = ar * 40 + akc * 8;
  // B: 256 rows x 4 chunks = 1024 -> 2 chunks/thread
  const unsigned short* bSrc[2];
  int bOff[2];
#pragma unroll
  for (int p = 0; p < 2; p++) {
    int c = tid + p * 512;
    int row = c >> 2, kc = c & 3;
    int sel = (row >> 4) & 1;
    int h = ht * 128 + ((row >> 5) << 4) + (row & 15);
    bSrc[p] = (sel ? Sub : Sgb) + (size_t)(s * HSH + h) * DDIM + kc * 8;
    bOff[p] = row * 40 + kc * 8;
  }

  us8 aReg = *reinterpret_cast<const us8*>(aSrc);
  us8 bReg[2];
#pragma unroll
  for (int p = 0; p < 2; p++) bReg[p] = *reinterpret_cast<const us8*>(bSrc[p]);

  f32x4 acc[4][4];
#pragma unroll
  for (int mf = 0; mf < 4; mf++)
#pragma unroll
    for (int nf = 0; nf < 4; nf++) acc[mf][nf] = {0.f, 0.f, 0.f, 0.f};

  int cur = 0;
  for (int step = 0; step < 32; ++step) {
    *reinterpret_cast<us8*>(&sA[cur][aOff]) = aReg;
#pragma unroll
    for (int p = 0; p < 2; p++) *reinterpret_cast<us8*>(&sB[cur][bOff[p]]) = bReg[p];
    if (step < 31) {
      int k0 = (step + 1) * 32;
      aReg = *reinterpret_cast<const us8*>(aSrc + k0);
#pragma unroll
      for (int p = 0; p < 2; p++) bReg[p] = *reinterpret_cast<const us8*>(bSrc[p] + k0);
    }
    pipe_barrier();
    int ka = (lane >> 4) * 8;
    bf16x8 a[4];
#pragma unroll
    for (int mf = 0; mf < 4; mf++)
      a[mf] = *reinterpret_cast<const bf16x8*>(&sA[cur][(wm * 64 + mf * 16 + (lane & 15)) * 40 + ka]);
#pragma unroll
    for (int nf = 0; nf < 4; nf++) {
      bf16x8 b = *reinterpret_cast<const bf16x8*>(&sB[cur][(wn * 64 + nf * 16 + (lane & 15)) * 40 + ka]);
#pragma unroll
      for (int mf = 0; mf < 4; mf++)
        acc[mf][nf] = __builtin_amdgcn_mfma_f32_16x16x32_bf16(a[mf], b, acc[mf][nf], 0, 0, 0);
    }
    cur ^= 1;
  }
  // wave col c = wn*64+nf*16: sel = nf&1, h16-block = wn*2 + (nf>>1)
#pragma unroll
  for (int mf = 0; mf < 4; mf++) {
#pragma unroll
    for (int t = 0; t < 2; t++) {
#pragma unroll
      for (int r = 0; r < 4; r++) {
        int tok = mt * 128 + wm * 64 + mf * 16 + ((lane >> 4) << 2) + r;
        float g = acc[mf][2 * t][r], u = acc[mf][2 * t + 1][r];
        float hval = (g / (1.f + __expf(-g))) * u;
        int h = ht * 128 + (wn * 2 + t) * 16 + (lane & 15);
        hs[(size_t)(tok * NSH + s) * HSH + h] = f2bf(hval);
      }
    }
  }
}

// ---------------- shared down-proj (per-s bf16 partial) ----------------
// grid (x = dh*2+s [16], y = mt [16]). 512 thr, 8 waves (2M x 4N).
// tile 128 rows x 128 d-cols (wave = 64x32), K=1024.
__global__ __launch_bounds__(512) void k_shared_down(const unsigned short* __restrict__ hs,
                                                     const unsigned short* __restrict__ Sdb,
                                                     unsigned short* __restrict__ Psh) {
  int dh = blockIdx.x >> 1, s = blockIdx.x & 1;
  int mt = blockIdx.y;
  __shared__ unsigned short sA[2][128 * 40];
  __shared__ unsigned short sB[2][128 * 40];
  int tid = threadIdx.x, lane = tid & 63, wid = tid >> 6;
  int wm = wid >> 2, wn = wid & 3;

  int ar = tid >> 2, akc = tid & 3;
  const unsigned short* aSrc = hs + (size_t)((mt * 128 + ar) * NSH + s) * HSH + akc * 8;
  int aOff = ar * 40 + akc * 8;
  int br = tid >> 2, bkc = tid & 3;
  const unsigned short* bSrc = Sdb + (size_t)(s * DDIM + dh * 128 + br) * HSH + bkc * 8;
  int bOff = br * 40 + bkc * 8;

  us8 aReg = *reinterpret_cast<const us8*>(aSrc);
  us8 bReg = *reinterpret_cast<const us8*>(bSrc);

  f32x4 acc[4][2];
#pragma unroll
  for (int mf = 0; mf < 4; mf++)
#pragma unroll
    for (int nf = 0; nf < 2; nf++) acc[mf][nf] = {0.f, 0.f, 0.f, 0.f};

  int cur = 0;
  for (int step = 0; step < 32; ++step) {
    *reinterpret_cast<us8*>(&sA[cur][aOff]) = aReg;
    *reinterpret_cast<us8*>(&sB[cur][bOff]) = bReg;
    if (step < 31) {
      int k0 = (step + 1) * 32;
      aReg = *reinterpret_cast<const us8*>(aSrc + k0);
      bReg = *reinterpret_cast<const us8*>(bSrc + k0);
    }
    pipe_barrier();
    int ka = (lane >> 4) * 8;
    bf16x8 a[4];
#pragma unroll
    for (int mf = 0; mf < 4; mf++)
      a[mf] = *reinterpret_cast<const bf16x8*>(&sA[cur][(wm * 64 + mf * 16 + (lane & 15)) * 40 + ka]);
#pragma unroll
    for (int nf = 0; nf < 2; nf++) {
      bf16x8 b = *reinterpret_cast<const bf16x8*>(&sB[cur][(wn * 32 + nf * 16 + (lane & 15)) * 40 + ka]);
#pragma unroll
      for (int mf = 0; mf < 4; mf++)
        acc[mf][nf] = __builtin_amdgcn_mfma_f32_16x16x32_bf16(a[mf], b, acc[mf][nf], 0, 0, 0);
    }
    cur ^= 1;
  }
#pragma unroll
  for (int mf = 0; mf < 4; mf++) {
#pragma unroll
    for (int nf = 0; nf < 2; nf++) {
#pragma unroll
      for (int r = 0; r < 4; r++) {
        int tok = mt * 128 + wm * 64 + mf * 16 + ((lane >> 4) << 2) + r;
        int d = dh * 128 + wn * 32 + nf * 16 + (lane & 15);
        Psh[(size_t)s * N_TOK * DDIM + (size_t)tok * DDIM + d] = f2bf(acc[mf][nf][r]);
      }
    }
  }
}

// ---------------- final combine ----------------
__global__ __launch_bounds__(256) void k_combine(const unsigned short* __restrict__ Pslot,
                                                 const unsigned short* __restrict__ Psh,
                                                 float* __restrict__ out) {
  int i = blockIdx.x * 256 + threadIdx.x;
  int base = i * 8;
  int tok = base >> 10, d = base & 1023;
  const us8 p0 = *reinterpret_cast<const us8*>(Pslot + ((size_t)tok * 4 + 0) * DDIM + d);
  const us8 p1 = *reinterpret_cast<const us8*>(Pslot + ((size_t)tok * 4 + 1) * DDIM + d);
  const us8 p2 = *reinterpret_cast<const us8*>(Pslot + ((size_t)tok * 4 + 2) * DDIM + d);
  const us8 p3 = *reinterpret_cast<const us8*>(Pslot + ((size_t)tok * 4 + 3) * DDIM + d);
  const us8 q0 = *reinterpret_cast<const us8*>(Psh + (size_t)base);
  const us8 q1 = *reinterpret_cast<const us8*>(Psh + (size_t)N_TOK * DDIM + base);
  float o[8];
#pragma unroll
  for (int j = 0; j < 8; j++)
    o[j] = bf2f(p0[j]) + bf2f(p1[j]) + bf2f(p2[j]) + bf2f(p3[j]) + bf2f(q0[j]) + bf2f(q1[j]);
  float4 v0 = {o[0], o[1], o[2], o[3]};
  float4 v1 = {o[4], o[5], o[6], o[7]};
  reinterpret_cast<float4*>(out + base)[0] = v0;
  reinterpret_cast<float4*>(out + base)[1] = v1;
}

extern "C" void kernel_launch(void* const* d_in, const int* in_sizes, int n_in,
                              void* d_out, int out_size, void* d_ws, size_t ws_size,
                              hipStream_t stream) {
  const float* x  = (const float*)d_in[0];
  const float* Wr = (const float*)d_in[1];
  const float* rb = (const float*)d_in[2];
  const float* Wg = (const float*)d_in[3];
  const float* Wu = (const float*)d_in[4];
  const float* Wd = (const float*)d_in[5];
  const float* Sg = (const float*)d_in[6];
  const float* Su = (const float*)d_in[7];
  const float* Sd = (const float*)d_in[8];
  float* out = (float*)d_out;
  char* w = (char*)d_ws;

  unsigned short* xb    = (unsigned short*)(w + (size_t)0);            // 4MB
  unsigned short* Wgb   = (unsigned short*)(w + ((size_t)4  << 20));   // 16MB
  unsigned short* Wub   = (unsigned short*)(w + ((size_t)20 << 20));   // 16MB
  unsigned short* Wdb   = (unsigned short*)(w + ((size_t)36 << 20));   // 16MB
  unsigned short* Sgb   = (unsigned short*)(w + ((size_t)52 << 20));   // 4MB
  unsigned short* Sub   = (unsigned short*)(w + ((size_t)56 << 20));   // 4MB
  unsigned short* Sdb   = (unsigned short*)(w + ((size_t)60 << 20));   // 4MB
  unsigned short* hw    = (unsigned short*)(w + ((size_t)64 << 20));   // 4MB
  unsigned short* hs    = (unsigned short*)(w + ((size_t)68 << 20));   // 8MB
  unsigned short* Pslot = (unsigned short*)(w + ((size_t)76 << 20));   // 16MB
  unsigned short* Psh   = (unsigned short*)(w + ((size_t)92 << 20));   // 8MB
  int*   cnt = (int*)(w + ((size_t)100 << 20));
  int*   ent = (int*)(w + ((size_t)100 << 20) + 8192);
  float* wgt = (float*)(w + ((size_t)100 << 20) + 8192 + (size_t)NEXP * N_TOK * 4);
  int*   wk   = (int*)(w + ((size_t)102 << 20));
  int*   nwk  = (int*)(w + ((size_t)102 << 20) + 4096);
  int*   wk2  = (int*)(w + ((size_t)102 << 20) + 8192);
  int*   nwk2 = (int*)(w + ((size_t)102 << 20) + 12288);

  hipMemsetAsync(cnt, 0, NEXP * CNTS * sizeof(int), stream);

  k_prep<<<256 + NCVT, 256, 0, stream>>>(x, Wr, rb, Wg, Wu, Wd, Sg, Su, Sd,
                                         xb, Wgb, Wub, Wdb, Sgb, Sub, Sdb,
                                         cnt, ent, wgt);
  k_plan<<<1, 64, 0, stream>>>(cnt, wk, nwk, wk2, nwk2);

  k_routed_gu<<<dim3(WM2, 4), 512, 0, stream>>>(xb, Wgb, Wub, cnt, ent, wgt, hw, wk2, nwk2);
  k_routed_down<<<dim3(WMAX, 4), 256, 0, stream>>>(hw, Wdb, cnt, ent, Pslot, wk, nwk);

  k_shared_gu<<<dim3(16, 16), 512, 0, stream>>>(xb, Sgb, Sub, hs);
  k_shared_down<<<dim3(16, 16), 512, 0, stream>>>(hs, Sdb, Psh);

  k_combine<<<N_TOK * DDIM / (256 * 8), 256, 0, stream>>>(Pslot, Psh, out);
}

// Round 14
// 161.867 us; speedup vs baseline: 1.0550x; 1.0142x over previous
//
#include <hip/hip_runtime.h>
#include <hip/hip_bf16.h>

// MoE FFN: B=2,T=1024,D=1024, E=32,H=256,TOPK=4, S=2,HS=1024. N=2048 tokens.
// Round 14: (1) cvt path: 32B loads + 16B uint4 stores per thread (flat
// sequential chunk map kept). (2) routed_down -> 128x128 tiles @ 512thr/8
// waves (r12's proven routed_gu structure), grid (wk2, dh=8).
// All else identical to r13 (164.2 us, passed).

#define N_TOK 2048
#define DDIM 1024
#define NEXP 32
#define HDIM 256
#define TOPK 4
#define NSH 2
#define HSH 1024
#define CNTS 32
#define WMAX 160
#define WM2  96

typedef unsigned short us4 __attribute__((ext_vector_type(4)));
typedef unsigned short us8 __attribute__((ext_vector_type(8)));
typedef short bf16x8 __attribute__((ext_vector_type(8)));
typedef float f32x4 __attribute__((ext_vector_type(4)));

__device__ __forceinline__ unsigned short f2bf(float f) {
  union { float f; unsigned u; } v; v.f = f;
  unsigned r = v.u + 0x7fffu + ((v.u >> 16) & 1u);   // RNE
  return (unsigned short)(r >> 16);
}
__device__ __forceinline__ float bf2f(unsigned short h) {
  union { unsigned u; float f; } v; v.u = ((unsigned)h) << 16; return v.f;
}
// packed conversion: compiler emits v_cvt_pk_bf16_f32
__device__ __forceinline__ uint2 cvt4u(float4 v) {
  union { __hip_bfloat162 b; unsigned u; } a, b2;
  a.b  = __float22bfloat162_rn(make_float2(v.x, v.y));
  b2.b = __float22bfloat162_rn(make_float2(v.z, v.w));
  return make_uint2(a.u, b2.u);
}

__device__ __forceinline__ void pipe_barrier() {
  asm volatile("s_waitcnt lgkmcnt(0)" ::: "memory");
  __builtin_amdgcn_s_barrier();
  __builtin_amdgcn_sched_barrier(0);   // pin ds_reads BELOW the barrier
}

// ---------------- prep: router (blocks 0..255, LDS-staged) + flat cvt ----------------
// segment ends in float4 units (all divisible by 512)
#define C_X4   524288L
#define C_WG4  2621440L
#define C_WU4  4718592L
#define C_WD4  6815744L
#define C_SG4  7340032L
#define C_SU4  7864320L
#define C_TOT4 8388608L
#define NCVT   16384

__global__ __launch_bounds__(256) void k_prep(const float* __restrict__ x,
                                              const float* __restrict__ Wr,
                                              const float* __restrict__ rb,
                                              const float* __restrict__ Wg,
                                              const float* __restrict__ Wu,
                                              const float* __restrict__ Wd,
                                              const float* __restrict__ Sg,
                                              const float* __restrict__ Su,
                                              const float* __restrict__ Sd,
                                              unsigned short* __restrict__ xb,
                                              unsigned short* __restrict__ Wgb,
                                              unsigned short* __restrict__ Wub,
                                              unsigned short* __restrict__ Wdb,
                                              unsigned short* __restrict__ Sgb,
                                              unsigned short* __restrict__ Sub,
                                              unsigned short* __restrict__ Sdb,
                                              int* __restrict__ cnt,
                                              int* __restrict__ ent,
                                              float* __restrict__ wgt) {
  __shared__ float sX[8 * 1024];
  __shared__ float sLog[8 * 32];
  int tid = threadIdx.x;
  if (blockIdx.x >= 256) {
    // ---- cvt: block -> contiguous 512-float4 chunk; 32B loads + 16B store/thread
    long base = (long)(blockIdx.x - 256) * 512;
    const float* s; unsigned short* d; long off;
    if (base < C_WG4) {
      if (base < C_X4)  { s = x;  d = xb;  off = base; }
      else              { s = Wg; d = Wgb; off = base - C_X4; }
    } else if (base < C_WD4) {
      if (base < C_WU4) { s = Wu; d = Wub; off = base - C_WG4; }
      else              { s = Wd; d = Wdb; off = base - C_WU4; }
    } else if (base < C_SU4) {
      if (base < C_SG4) { s = Sg; d = Sgb; off = base - C_WD4; }
      else              { s = Su; d = Sub; off = base - C_SG4; }
    } else              { s = Sd; d = Sdb; off = base - C_SU4; }
    long i0 = off + 2 * tid;
    float4 v0 = reinterpret_cast<const float4*>(s)[i0];
    float4 v1 = reinterpret_cast<const float4*>(s)[i0 + 1];
    uint2 a = cvt4u(v0), b = cvt4u(v1);
    uint4 o = make_uint4(a.x, a.y, b.x, b.y);
    reinterpret_cast<uint4*>(d)[(off >> 1) + tid] = o;
    return;
  }
  // ---- router path (r2-proven): stage 8 x-rows in LDS, thread = (tok, e) dot
  int blk = blockIdx.x;
  {
    const float4* xsrc = reinterpret_cast<const float4*>(x + (size_t)blk * 8 * 1024);
    float4* xdst = reinterpret_cast<float4*>(sX);
#pragma unroll
    for (int i = 0; i < 8; i++) xdst[tid + 256 * i] = xsrc[tid + 256 * i];
  }
  __syncthreads();
  int tloc = tid >> 5, e = tid & 31;
  const float4* wr4 = reinterpret_cast<const float4*>(Wr + (size_t)e * DDIM);
  const float* xr = sX + tloc * 1024;
  float acc = 0.f;
#pragma unroll 8
  for (int d4 = 0; d4 < 256; d4++) {
    float4 wv = wr4[d4];
    acc += xr[d4 * 4 + 0] * wv.x + xr[d4 * 4 + 1] * wv.y +
           xr[d4 * 4 + 2] * wv.z + xr[d4 * 4 + 3] * wv.w;
  }
  sLog[tloc * 32 + e] = acc;
  __syncthreads();
  if (tid < 8) {
    int tok = blk * 8 + tid;
    const float* lg = sLog + tid * 32;
    int usedmask = 0;
    int idx[TOPK]; float lv[TOPK];
#pragma unroll
    for (int k = 0; k < TOPK; k++) {
      float best = -3.4e38f; int bi = 0;
      for (int ee = 0; ee < NEXP; ee++) {
        if ((usedmask >> ee) & 1) continue;
        float v = lg[ee] + rb[ee];
        if (v > best) { best = v; bi = ee; }
      }
      usedmask |= 1 << bi; idx[k] = bi; lv[k] = lg[bi];
    }
    float m = fmaxf(fmaxf(lv[0], lv[1]), fmaxf(lv[2], lv[3]));
    float w[TOPK]; float ssum = 0.f;
#pragma unroll
    for (int k = 0; k < TOPK; k++) { w[k] = __expf(lv[k] - m); ssum += w[k]; }
    float inv = 1.f / ssum;
#pragma unroll
    for (int k = 0; k < TOPK; k++) {
      int ee = idx[k];
      int pos = atomicAdd(&cnt[ee * CNTS], 1);
      ent[ee * N_TOK + pos] = tok * TOPK + k;
      wgt[ee * N_TOK + pos] = w[k] * inv;
    }
  }
}

// ---------------- work-list builder: 64- and 128-granularity ----------------
__global__ void k_plan(const int* __restrict__ cnt, int* __restrict__ wk, int* __restrict__ nwk,
                       int* __restrict__ wk2, int* __restrict__ nwk2) {
  if (threadIdx.x != 0) return;
  int w = 0, w2 = 0;
  for (int e = 0; e < NEXP; e++) {
    int ne = cnt[e * CNTS];
    int nt = (ne + 63) >> 6;
    for (int t = 0; t < nt; t++) wk[w++] = e | (t << 8);
    int nt2 = (ne + 127) >> 7;
    for (int t = 0; t < nt2; t++) wk2[w2++] = e | (t << 8);
  }
  nwk[0] = w;
  nwk2[0] = w2;
}

// ---------------- routed gate+up (+swiglu) ----------------
// grid (WM2, ht=4), 512 thr, 8 waves (2M x 4N). tile 128 gathered rows x 128
// cols (64 g | 64 u interleaved at 16; wave = 64 rows x 32 cols).
__global__ __launch_bounds__(512) void k_routed_gu(const unsigned short* __restrict__ xb,
                                                   const unsigned short* __restrict__ Wgb,
                                                   const unsigned short* __restrict__ Wub,
                                                   const int* __restrict__ cnt,
                                                   const int* __restrict__ ent,
                                                   const float* __restrict__ wgt,
                                                   unsigned short* __restrict__ hw,
                                                   const int* __restrict__ wk2,
                                                   const int* __restrict__ nwk2) {
  int widx = blockIdx.x;
  if (widx >= nwk2[0]) return;
  int item = wk2[widx];
  int e = item & 255, mt = item >> 8, ht = blockIdx.y;
  int ne = cnt[e * CNTS];
  __shared__ unsigned short sA[2][128 * 40];
  __shared__ unsigned short sB[2][128 * 40];
  __shared__ int sTok[128];
  __shared__ float sW[128];
  int tid = threadIdx.x, lane = tid & 63, wid = tid >> 6;
  int wm = wid >> 2, wn = wid & 3;
  if (tid < 128) {
    int pos = mt * 128 + tid;
    int p2 = min(pos, ne - 1);
    sTok[tid] = ent[e * N_TOK + p2];
    sW[tid] = (pos < ne) ? wgt[e * N_TOK + p2] : 0.f;
  }
  __syncthreads();

  int ar = tid >> 2, akc = tid & 3;
  const unsigned short* aSrc = xb + (size_t)(sTok[ar] >> 2) * DDIM + akc * 8;
  int aOff = ar * 40 + akc * 8;
  int br = tid >> 2, bkc = tid & 3;
  int sel = (br >> 4) & 1;
  int h = ht * 64 + ((br >> 5) << 4) + (br & 15);
  const unsigned short* bSrc = (sel ? Wub : Wgb) + (size_t)(e * HDIM + h) * DDIM + bkc * 8;
  int bOff = br * 40 + bkc * 8;

  us8 aReg = *reinterpret_cast<const us8*>(aSrc);
  us8 bReg = *reinterpret_cast<const us8*>(bSrc);

  f32x4 acc[4][2];
#pragma unroll
  for (int mf = 0; mf < 4; mf++)
#pragma unroll
    for (int nf = 0; nf < 2; nf++) acc[mf][nf] = {0.f, 0.f, 0.f, 0.f};

  int cur = 0;
  for (int step = 0; step < 32; ++step) {
    *reinterpret_cast<us8*>(&sA[cur][aOff]) = aReg;
    *reinterpret_cast<us8*>(&sB[cur][bOff]) = bReg;
    if (step < 31) {
      int k0 = (step + 1) * 32;
      aReg = *reinterpret_cast<const us8*>(aSrc + k0);
      bReg = *reinterpret_cast<const us8*>(bSrc + k0);
    }
    pipe_barrier();
    int ka = (lane >> 4) * 8;
    bf16x8 a[4];
#pragma unroll
    for (int mf = 0; mf < 4; mf++)
      a[mf] = *reinterpret_cast<const bf16x8*>(&sA[cur][(wm * 64 + mf * 16 + (lane & 15)) * 40 + ka]);
#pragma unroll
    for (int nf = 0; nf < 2; nf++) {
      bf16x8 b = *reinterpret_cast<const bf16x8*>(&sB[cur][(wn * 32 + nf * 16 + (lane & 15)) * 40 + ka]);
#pragma unroll
      for (int mf = 0; mf < 4; mf++)
        acc[mf][nf] = __builtin_amdgcn_mfma_f32_16x16x32_bf16(a[mf], b, acc[mf][nf], 0, 0, 0);
    }
    cur ^= 1;
  }
  // wave col c = wn*32 + nf*16 + i: sel = nf (g/u), h = ht*64 + wn*16 + i
#pragma unroll
  for (int mf = 0; mf < 4; mf++) {
#pragma unroll
    for (int r = 0; r < 4; r++) {
      int tl = wm * 64 + mf * 16 + ((lane >> 4) << 2) + r;
      int pos = mt * 128 + tl;
      if (pos < ne) {
        float g = acc[mf][0][r], u = acc[mf][1][r];
        float hval = (g / (1.f + __expf(-g))) * u * sW[tl];
        int ts = sTok[tl];
        int hcol = ht * 64 + wn * 16 + (lane & 15);
        hw[(size_t)ts * HDIM + hcol] = f2bf(hval);
      }
    }
  }
}

// ---------------- routed down-proj (bf16 per-slot store) ----------------
// grid (WM2, dh=8), 512 thr, 8 waves (2M x 4N). tile 128 gathered rows x 128
// d-cols (wave = 64 x 32), K=256 in 8 steps.
__global__ __launch_bounds__(512) void k_routed_down(const unsigned short* __restrict__ hw,
                                                     const unsigned short* __restrict__ Wdb,
                                                     const int* __restrict__ cnt,
                                                     const int* __restrict__ ent,
                                                     unsigned short* __restrict__ Pslot,
                                                     const int* __restrict__ wk2,
                                                     const int* __restrict__ nwk2) {
  int widx = blockIdx.x;
  if (widx >= nwk2[0]) return;
  int item = wk2[widx];
  int e = item & 255, mt = item >> 8, dh = blockIdx.y;
  int ne = cnt[e * CNTS];
  __shared__ unsigned short sA[2][128 * 40];
  __shared__ unsigned short sB[2][128 * 40];
  __shared__ int sTok[128];
  int tid = threadIdx.x, lane = tid & 63, wid = tid >> 6;
  int wm = wid >> 2, wn = wid & 3;
  if (tid < 128) {
    int pos = mt * 128 + tid;
    int p2 = min(pos, ne - 1);
    sTok[tid] = ent[e * N_TOK + p2];
  }
  __syncthreads();

  // A: 128 rows x 256 K; per step 32 K -> 128 rows x 4 chunks = 512 = 1/thread
  int ar = tid >> 2, akc = tid & 3;
  const unsigned short* aSrc = hw + (size_t)sTok[ar] * HDIM + akc * 8;
  int aOff = ar * 40 + akc * 8;
  int br = tid >> 2, bkc = tid & 3;
  int d0 = dh * 128 + br;
  const unsigned short* bSrc = Wdb + (size_t)(e * DDIM + d0) * HDIM + bkc * 8;
  int bOff = br * 40 + bkc * 8;

  us8 aReg = *reinterpret_cast<const us8*>(aSrc);
  us8 bReg = *reinterpret_cast<const us8*>(bSrc);

  f32x4 acc[4][2];
#pragma unroll
  for (int mf = 0; mf < 4; mf++)
#pragma unroll
    for (int nf = 0; nf < 2; nf++) acc[mf][nf] = {0.f, 0.f, 0.f, 0.f};

  int cur = 0;
  for (int step = 0; step < 8; ++step) {
    *reinterpret_cast<us8*>(&sA[cur][aOff]) = aReg;
    *reinterpret_cast<us8*>(&sB[cur][bOff]) = bReg;
    if (step < 7) {
      int k0 = (step + 1) * 32;
      aReg = *reinterpret_cast<const us8*>(aSrc + k0);
      bReg = *reinterpret_cast<const us8*>(bSrc + k0);
    }
    pipe_barrier();
    int ka = (lane >> 4) * 8;
    bf16x8 a[4];
#pragma unroll
    for (int mf = 0; mf < 4; mf++)
      a[mf] = *reinterpret_cast<const bf16x8*>(&sA[cur][(wm * 64 + mf * 16 + (lane & 15)) * 40 + ka]);
#pragma unroll
    for (int nf = 0; nf < 2; nf++) {
      bf16x8 b = *reinterpret_cast<const bf16x8*>(&sB[cur][(wn * 32 + nf * 16 + (lane & 15)) * 40 + ka]);
#pragma unroll
      for (int mf = 0; mf < 4; mf++)
        acc[mf][nf] = __builtin_amdgcn_mfma_f32_16x16x32_bf16(a[mf], b, acc[mf][nf], 0, 0, 0);
    }
    cur ^= 1;
  }
#pragma unroll
  for (int mf = 0; mf < 4; mf++) {
#pragma unroll
    for (int nf = 0; nf < 2; nf++) {
#pragma unroll
      for (int r = 0; r < 4; r++) {
        int tl = wm * 64 + mf * 16 + ((lane >> 4) << 2) + r;
        int pos = mt * 128 + tl;
        if (pos < ne) {
          int ts = sTok[tl];
          int d = dh * 128 + wn * 32 + nf * 16 + (lane & 15);
          Pslot[(size_t)ts * DDIM + d] = f2bf(acc[mf][nf][r]);
        }
      }
    }
  }
}

// ---------------- shared gate+up (+swiglu) ----------------
// grid (x = s*8+ht [16], y = mt [16]). 512 thr, 8 waves (2M x 4N).
// tile 128 rows x 256 cols (128 g | 128 u interleaved at 16), K=1024.
__global__ __launch_bounds__(512) void k_shared_gu(const unsigned short* __restrict__ xb,
                                                   const unsigned short* __restrict__ Sgb,
                                                   const unsigned short* __restrict__ Sub,
                                                   unsigned short* __restrict__ hs) {
  int s = blockIdx.x >> 3, ht = blockIdx.x & 7;
  int mt = blockIdx.y;
  __shared__ unsigned short sA[2][128 * 40];
  __shared__ unsigned short sB[2][256 * 40];
  int tid = threadIdx.x, lane = tid & 63, wid = tid >> 6;
  int wm = wid >> 2, wn = wid & 3;

  int ar = tid >> 2, akc = tid & 3;
  const unsigned short* aSrc = xb + (size_t)(mt * 128 + ar) * DDIM + akc * 8;
  int aOff = ar * 40 + akc * 8;
  const unsigned short* bSrc[2];
  int bOff[2];
#pragma unroll
  for (int p = 0; p < 2; p++) {
    int c = tid + p * 512;
    int row = c >> 2, kc = c & 3;
    int sel = (row >> 4) & 1;
    int h = ht * 128 + ((row >> 5) << 4) + (row & 15);
    bSrc[p] = (sel ? Sub : Sgb) + (size_t)(s * HSH + h) * DDIM + kc * 8;
    bOff[p] = row * 40 + kc * 8;
  }

  us8 aReg = *reinterpret_cast<const us8*>(aSrc);
  us8 bReg[2];
#pragma unroll
  for (int p = 0; p < 2; p++) bReg[p] = *reinterpret_cast<const us8*>(bSrc[p]);

  f32x4 acc[4][4];
#pragma unroll
  for (int mf = 0; mf < 4; mf++)
#pragma unroll
    for (int nf = 0; nf < 4; nf++) acc[mf][nf] = {0.f, 0.f, 0.f, 0.f};

  int cur = 0;
  for (int step = 0; step < 32; ++step) {
    *reinterpret_cast<us8*>(&sA[cur][aOff]) = aReg;
#pragma unroll
    for (int p = 0; p < 2; p++) *reinterpret_cast<us8*>(&sB[cur][bOff[p]]) = bReg[p];
    if (step < 31) {
      int k0 = (step + 1) * 32;
      aReg = *reinterpret_cast<const us8*>(aSrc + k0);
#pragma unroll
      for (int p = 0; p < 2; p++) bReg[p] = *reinterpret_cast<const us8*>(bSrc[p] + k0);
    }
    pipe_barrier();
    int ka = (lane >> 4) * 8;
    bf16x8 a[4];
#pragma unroll
    for (int mf = 0; mf < 4; mf++)
      a[mf] = *reinterpret_cast<const bf16x8*>(&sA[cur][(wm * 64 + mf * 16 + (lane & 15)) * 40 + ka]);
#pragma unroll
    for (int nf = 0; nf < 4; nf++) {
      bf16x8 b = *reinterpret_cast<const bf16x8*>(&sB[cur][(wn * 64 + nf * 16 + (lane & 15)) * 40 + ka]);
#pragma unroll
      for (int mf = 0; mf < 4; mf++)
        acc[mf][nf] = __builtin_amdgcn_mfma_f32_16x16x32_bf16(a[mf], b, acc[mf][nf], 0, 0, 0);
    }
    cur ^= 1;
  }
  // wave col c = wn*64+nf*16: sel = nf&1, h16-block = wn*2 + (nf>>1)
#pragma unroll
  for (int mf = 0; mf < 4; mf++) {
#pragma unroll
    for (int t = 0; t < 2; t++) {
#pragma unroll
      for (int r = 0; r < 4; r++) {
        int tok = mt * 128 + wm * 64 + mf * 16 + ((lane >> 4) << 2) + r;
        float g = acc[mf][2 * t][r], u = acc[mf][2 * t + 1][r];
        float hval = (g / (1.f + __expf(-g))) * u;
        int h = ht * 128 + (wn * 2 + t) * 16 + (lane & 15);
        hs[(size_t)(tok * NSH + s) * HSH + h] = f2bf(hval);
      }
    }
  }
}

// ---------------- shared down-proj (per-s bf16 partial) ----------------
// grid (x = dh*2+s [16], y = mt [16]). 512 thr, 8 waves (2M x 4N).
// tile 128 rows x 128 d-cols (wave = 64x32), K=1024.
__global__ __launch_bounds__(512) void k_shared_down(const unsigned short* __restrict__ hs,
                                                     const unsigned short* __restrict__ Sdb,
                                                     unsigned short* __restrict__ Psh) {
  int dh = blockIdx.x >> 1, s = blockIdx.x & 1;
  int mt = blockIdx.y;
  __shared__ unsigned short sA[2][128 * 40];
  __shared__ unsigned short sB[2][128 * 40];
  int tid = threadIdx.x, lane = tid & 63, wid = tid >> 6;
  int wm = wid >> 2, wn = wid & 3;

  int ar = tid >> 2, akc = tid & 3;
  const unsigned short* aSrc = hs + (size_t)((mt * 128 + ar) * NSH + s) * HSH + akc * 8;
  int aOff = ar * 40 + akc * 8;
  int br = tid >> 2, bkc = tid & 3;
  const unsigned short* bSrc = Sdb + (size_t)(s * DDIM + dh * 128 + br) * HSH + bkc * 8;
  int bOff = br * 40 + bkc * 8;

  us8 aReg = *reinterpret_cast<const us8*>(aSrc);
  us8 bReg = *reinterpret_cast<const us8*>(bSrc);

  f32x4 acc[4][2];
#pragma unroll
  for (int mf = 0; mf < 4; mf++)
#pragma unroll
    for (int nf = 0; nf < 2; nf++) acc[mf][nf] = {0.f, 0.f, 0.f, 0.f};

  int cur = 0;
  for (int step = 0; step < 32; ++step) {
    *reinterpret_cast<us8*>(&sA[cur][aOff]) = aReg;
    *reinterpret_cast<us8*>(&sB[cur][bOff]) = bReg;
    if (step < 31) {
      int k0 = (step + 1) * 32;
      aReg = *reinterpret_cast<const us8*>(aSrc + k0);
      bReg = *reinterpret_cast<const us8*>(bSrc + k0);
    }
    pipe_barrier();
    int ka = (lane >> 4) * 8;
    bf16x8 a[4];
#pragma unroll
    for (int mf = 0; mf < 4; mf++)
      a[mf] = *reinterpret_cast<const bf16x8*>(&sA[cur][(wm * 64 + mf * 16 + (lane & 15)) * 40 + ka]);
#pragma unroll
    for (int nf = 0; nf < 2; nf++) {
      bf16x8 b = *reinterpret_cast<const bf16x8*>(&sB[cur][(wn * 32 + nf * 16 + (lane & 15)) * 40 + ka]);
#pragma unroll
      for (int mf = 0; mf < 4; mf++)
        acc[mf][nf] = __builtin_amdgcn_mfma_f32_16x16x32_bf16(a[mf], b, acc[mf][nf], 0, 0, 0);
    }
    cur ^= 1;
  }
#pragma unroll
  for (int mf = 0; mf < 4; mf++) {
#pragma unroll
    for (int nf = 0; nf < 2; nf++) {
#pragma unroll
      for (int r = 0; r < 4; r++) {
        int tok = mt * 128 + wm * 64 + mf * 16 + ((lane >> 4) << 2) + r;
        int d = dh * 128 + wn * 32 + nf * 16 + (lane & 15);
        Psh[(size_t)s * N_TOK * DDIM + (size_t)tok * DDIM + d] = f2bf(acc[mf][nf][r]);
      }
    }
  }
}

// ---------------- final combine ----------------
__global__ __launch_bounds__(256) void k_combine(const unsigned short* __restrict__ Pslot,
                                                 const unsigned short* __restrict__ Psh,
                                                 float* __restrict__ out) {
  int i = blockIdx.x * 256 + threadIdx.x;
  int base = i * 8;
  int tok = base >> 10, d = base & 1023;
  const us8 p0 = *reinterpret_cast<const us8*>(Pslot + ((size_t)tok * 4 + 0) * DDIM + d);
  const us8 p1 = *reinterpret_cast<const us8*>(Pslot + ((size_t)tok * 4 + 1) * DDIM + d);
  const us8 p2 = *reinterpret_cast<const us8*>(Pslot + ((size_t)tok * 4 + 2) * DDIM + d);
  const us8 p3 = *reinterpret_cast<const us8*>(Pslot + ((size_t)tok * 4 + 3) * DDIM + d);
  const us8 q0 = *reinterpret_cast<const us8*>(Psh + (size_t)base);
  const us8 q1 = *reinterpret_cast<const us8*>(Psh + (size_t)N_TOK * DDIM + base);
  float o[8];
#pragma unroll
  for (int j = 0; j < 8; j++)
    o[j] = bf2f(p0[j]) + bf2f(p1[j]) + bf2f(p2[j]) + bf2f(p3[j]) + bf2f(q0[j]) + bf2f(q1[j]);
  float4 v0 = {o[0], o[1], o[2], o[3]};
  float4 v1 = {o[4], o[5], o[6], o[7]};
  reinterpret_cast<float4*>(out + base)[0] = v0;
  reinterpret_cast<float4*>(out + base)[1] = v1;
}

extern "C" void kernel_launch(void* const* d_in, const int* in_sizes, int n_in,
                              void* d_out, int out_size, void* d_ws, size_t ws_size,
                              hipStream_t stream) {
  const float* x  = (const float*)d_in[0];
  const float* Wr = (const float*)d_in[1];
  const float* rb = (const float*)d_in[2];
  const float* Wg = (const float*)d_in[3];
  const float* Wu = (const float*)d_in[4];
  const float* Wd = (const float*)d_in[5];
  const float* Sg = (const float*)d_in[6];
  const float* Su = (const float*)d_in[7];
  const float* Sd = (const float*)d_in[8];
  float* out = (float*)d_out;
  char* w = (char*)d_ws;

  unsigned short* xb    = (unsigned short*)(w + (size_t)0);            // 4MB
  unsigned short* Wgb   = (unsigned short*)(w + ((size_t)4  << 20));   // 16MB
  unsigned short* Wub   = (unsigned short*)(w + ((size_t)20 << 20));   // 16MB
  unsigned short* Wdb   = (unsigned short*)(w + ((size_t)36 << 20));   // 16MB
  unsigned short* Sgb   = (unsigned short*)(w + ((size_t)52 << 20));   // 4MB
  unsigned short* Sub   = (unsigned short*)(w + ((size_t)56 << 20));   // 4MB
  unsigned short* Sdb   = (unsigned short*)(w + ((size_t)60 << 20));   // 4MB
  unsigned short* hw    = (unsigned short*)(w + ((size_t)64 << 20));   // 4MB
  unsigned short* hs    = (unsigned short*)(w + ((size_t)68 << 20));   // 8MB
  unsigned short* Pslot = (unsigned short*)(w + ((size_t)76 << 20));   // 16MB
  unsigned short* Psh   = (unsigned short*)(w + ((size_t)92 << 20));   // 8MB
  int*   cnt = (int*)(w + ((size_t)100 << 20));
  int*   ent = (int*)(w + ((size_t)100 << 20) + 8192);
  float* wgt = (float*)(w + ((size_t)100 << 20) + 8192 + (size_t)NEXP * N_TOK * 4);
  int*   wk   = (int*)(w + ((size_t)102 << 20));
  int*   nwk  = (int*)(w + ((size_t)102 << 20) + 4096);
  int*   wk2  = (int*)(w + ((size_t)102 << 20) + 8192);
  int*   nwk2 = (int*)(w + ((size_t)102 << 20) + 12288);

  hipMemsetAsync(cnt, 0, NEXP * CNTS * sizeof(int), stream);

  k_prep<<<256 + NCVT, 256, 0, stream>>>(x, Wr, rb, Wg, Wu, Wd, Sg, Su, Sd,
                                         xb, Wgb, Wub, Wdb, Sgb, Sub, Sdb,
                                         cnt, ent, wgt);
  k_plan<<<1, 64, 0, stream>>>(cnt, wk, nwk, wk2, nwk2);

  k_routed_gu<<<dim3(WM2, 4), 512, 0, stream>>>(xb, Wgb, Wub, cnt, ent, wgt, hw, wk2, nwk2);
  k_routed_down<<<dim3(WM2, 8), 512, 0, stream>>>(hw, Wdb, cnt, ent, Pslot, wk2, nwk2);

  k_shared_gu<<<dim3(16, 16), 512, 0, stream>>>(xb, Sgb, Sub, hs);
  k_shared_down<<<dim3(16, 16), 512, 0, stream>>>(hs, Sdb, Psh);

  k_combine<<<N_TOK * DDIM / (256 * 8), 256, 0, stream>>>(Pslot, Psh, out);
}

// Round 15
// 136.631 us; speedup vs baseline: 1.2498x; 1.1847x over previous
//
#include <hip/hip_runtime.h>
#include <hip/hip_bf16.h>

// MoE FFN: B=2,T=1024,D=1024, E=32,H=256,TOPK=4, S=2,HS=1024. N=2048 tokens.
// Round 15: (1) wave-parallel k_plan (32 thr + shfl prefix scan; was 1-thread
// serial latency). (2) GEMM fusion: k_gu = shared_gu(0..255)+routed_gu(256..639),
// k_down = shared_down(0..255)+routed_down(256..1023); LDS unioned via pool.
// Inner loops byte-identical to r14 (161.9 us, passed).

#define N_TOK 2048
#define DDIM 1024
#define NEXP 32
#define HDIM 256
#define TOPK 4
#define NSH 2
#define HSH 1024
#define CNTS 32
#define WM2  96

typedef unsigned short us4 __attribute__((ext_vector_type(4)));
typedef unsigned short us8 __attribute__((ext_vector_type(8)));
typedef short bf16x8 __attribute__((ext_vector_type(8)));
typedef float f32x4 __attribute__((ext_vector_type(4)));

__device__ __forceinline__ unsigned short f2bf(float f) {
  union { float f; unsigned u; } v; v.f = f;
  unsigned r = v.u + 0x7fffu + ((v.u >> 16) & 1u);   // RNE
  return (unsigned short)(r >> 16);
}
__device__ __forceinline__ float bf2f(unsigned short h) {
  union { unsigned u; float f; } v; v.u = ((unsigned)h) << 16; return v.f;
}
__device__ __forceinline__ uint2 cvt4u(float4 v) {
  union { __hip_bfloat162 b; unsigned u; } a, b2;
  a.b  = __float22bfloat162_rn(make_float2(v.x, v.y));
  b2.b = __float22bfloat162_rn(make_float2(v.z, v.w));
  return make_uint2(a.u, b2.u);
}

__device__ __forceinline__ void pipe_barrier() {
  asm volatile("s_waitcnt lgkmcnt(0)" ::: "memory");
  __builtin_amdgcn_s_barrier();
  __builtin_amdgcn_sched_barrier(0);   // pin ds_reads BELOW the barrier
}

// ---------------- prep: router (blocks 0..255, LDS-staged) + flat cvt ----------------
#define C_X4   524288L
#define C_WG4  2621440L
#define C_WU4  4718592L
#define C_WD4  6815744L
#define C_SG4  7340032L
#define C_SU4  7864320L
#define C_TOT4 8388608L
#define NCVT   16384

__global__ __launch_bounds__(256) void k_prep(const float* __restrict__ x,
                                              const float* __restrict__ Wr,
                                              const float* __restrict__ rb,
                                              const float* __restrict__ Wg,
                                              const float* __restrict__ Wu,
                                              const float* __restrict__ Wd,
                                              const float* __restrict__ Sg,
                                              const float* __restrict__ Su,
                                              const float* __restrict__ Sd,
                                              unsigned short* __restrict__ xb,
                                              unsigned short* __restrict__ Wgb,
                                              unsigned short* __restrict__ Wub,
                                              unsigned short* __restrict__ Wdb,
                                              unsigned short* __restrict__ Sgb,
                                              unsigned short* __restrict__ Sub,
                                              unsigned short* __restrict__ Sdb,
                                              int* __restrict__ cnt,
                                              int* __restrict__ ent,
                                              float* __restrict__ wgt) {
  __shared__ float sX[8 * 1024];
  __shared__ float sLog[8 * 32];
  int tid = threadIdx.x;
  if (blockIdx.x >= 256) {
    long base = (long)(blockIdx.x - 256) * 512;
    const float* s; unsigned short* d; long off;
    if (base < C_WG4) {
      if (base < C_X4)  { s = x;  d = xb;  off = base; }
      else              { s = Wg; d = Wgb; off = base - C_X4; }
    } else if (base < C_WD4) {
      if (base < C_WU4) { s = Wu; d = Wub; off = base - C_WG4; }
      else              { s = Wd; d = Wdb; off = base - C_WU4; }
    } else if (base < C_SU4) {
      if (base < C_SG4) { s = Sg; d = Sgb; off = base - C_WD4; }
      else              { s = Su; d = Sub; off = base - C_SG4; }
    } else              { s = Sd; d = Sdb; off = base - C_SU4; }
    long i0 = off + 2 * tid;
    float4 v0 = reinterpret_cast<const float4*>(s)[i0];
    float4 v1 = reinterpret_cast<const float4*>(s)[i0 + 1];
    uint2 a = cvt4u(v0), b = cvt4u(v1);
    uint4 o = make_uint4(a.x, a.y, b.x, b.y);
    reinterpret_cast<uint4*>(d)[(off >> 1) + tid] = o;
    return;
  }
  int blk = blockIdx.x;
  {
    const float4* xsrc = reinterpret_cast<const float4*>(x + (size_t)blk * 8 * 1024);
    float4* xdst = reinterpret_cast<float4*>(sX);
#pragma unroll
    for (int i = 0; i < 8; i++) xdst[tid + 256 * i] = xsrc[tid + 256 * i];
  }
  __syncthreads();
  int tloc = tid >> 5, e = tid & 31;
  const float4* wr4 = reinterpret_cast<const float4*>(Wr + (size_t)e * DDIM);
  const float* xr = sX + tloc * 1024;
  float acc = 0.f;
#pragma unroll 8
  for (int d4 = 0; d4 < 256; d4++) {
    float4 wv = wr4[d4];
    acc += xr[d4 * 4 + 0] * wv.x + xr[d4 * 4 + 1] * wv.y +
           xr[d4 * 4 + 2] * wv.z + xr[d4 * 4 + 3] * wv.w;
  }
  sLog[tloc * 32 + e] = acc;
  __syncthreads();
  if (tid < 8) {
    int tok = blk * 8 + tid;
    const float* lg = sLog + tid * 32;
    int usedmask = 0;
    int idx[TOPK]; float lv[TOPK];
#pragma unroll
    for (int k = 0; k < TOPK; k++) {
      float best = -3.4e38f; int bi = 0;
      for (int ee = 0; ee < NEXP; ee++) {
        if ((usedmask >> ee) & 1) continue;
        float v = lg[ee] + rb[ee];
        if (v > best) { best = v; bi = ee; }
      }
      usedmask |= 1 << bi; idx[k] = bi; lv[k] = lg[bi];
    }
    float m = fmaxf(fmaxf(lv[0], lv[1]), fmaxf(lv[2], lv[3]));
    float w[TOPK]; float ssum = 0.f;
#pragma unroll
    for (int k = 0; k < TOPK; k++) { w[k] = __expf(lv[k] - m); ssum += w[k]; }
    float inv = 1.f / ssum;
#pragma unroll
    for (int k = 0; k < TOPK; k++) {
      int ee = idx[k];
      int pos = atomicAdd(&cnt[ee * CNTS], 1);
      ent[ee * N_TOK + pos] = tok * TOPK + k;
      wgt[ee * N_TOK + pos] = w[k] * inv;
    }
  }
}

// ---------------- wave-parallel work-list builder ----------------
__global__ void k_plan(const int* __restrict__ cnt, int* __restrict__ wk2, int* __restrict__ nwk2) {
  int e = threadIdx.x;
  if (e >= 32) return;
  int ne = cnt[e * CNTS];
  int nt2 = (ne + 127) >> 7;
  int off2 = 0;
  for (int j = 0; j < 32; j++) {
    int v2 = __shfl(nt2, j);
    if (j < e) off2 += v2;
  }
  for (int t = 0; t < nt2; t++) wk2[off2 + t] = e | (t << 8);
  if (e == 31) nwk2[0] = off2 + nt2;
}

// ---------------- fused gate+up: shared (blocks 0..255) + routed (256..639) ----------------
// shared: tile 128 x 256 (g|u interleaved 16), K=1024. routed: tile 128 x 128, K=1024.
__global__ __launch_bounds__(512) void k_gu(const unsigned short* __restrict__ xb,
                                            const unsigned short* __restrict__ Sgb,
                                            const unsigned short* __restrict__ Sub,
                                            const unsigned short* __restrict__ Wgb,
                                            const unsigned short* __restrict__ Wub,
                                            const int* __restrict__ cnt,
                                            const int* __restrict__ ent,
                                            const float* __restrict__ wgt,
                                            unsigned short* __restrict__ hs,
                                            unsigned short* __restrict__ hw,
                                            const int* __restrict__ wk2,
                                            const int* __restrict__ nwk2) {
  __shared__ unsigned short sPool[2 * 128 * 40 + 2 * 256 * 40];  // 61440 B
  __shared__ int sTok[128];
  __shared__ float sW[128];
  int tid = threadIdx.x, lane = tid & 63, wid = tid >> 6;
  int wm = wid >> 2, wn = wid & 3;
  int b = blockIdx.x;

  if (b < 256) {
    // ---------- shared_gu path (r14-identical inner loop) ----------
    int xg = b & 15, mt = b >> 4;
    int s = xg >> 3, ht = xg & 7;
    unsigned short* sA = sPool;                 // [2][128*40]
    unsigned short* sB = sPool + 2 * 128 * 40;  // [2][256*40]

    int ar = tid >> 2, akc = tid & 3;
    const unsigned short* aSrc = xb + (size_t)(mt * 128 + ar) * DDIM + akc * 8;
    int aOff = ar * 40 + akc * 8;
    const unsigned short* bSrc[2];
    int bOff[2];
#pragma unroll
    for (int p = 0; p < 2; p++) {
      int c = tid + p * 512;
      int row = c >> 2, kc = c & 3;
      int sel = (row >> 4) & 1;
      int h = ht * 128 + ((row >> 5) << 4) + (row & 15);
      bSrc[p] = (sel ? Sub : Sgb) + (size_t)(s * HSH + h) * DDIM + kc * 8;
      bOff[p] = row * 40 + kc * 8;
    }

    us8 aReg = *reinterpret_cast<const us8*>(aSrc);
    us8 bReg[2];
#pragma unroll
    for (int p = 0; p < 2; p++) bReg[p] = *reinterpret_cast<const us8*>(bSrc[p]);

    f32x4 acc[4][4];
#pragma unroll
    for (int mf = 0; mf < 4; mf++)
#pragma unroll
      for (int nf = 0; nf < 4; nf++) acc[mf][nf] = {0.f, 0.f, 0.f, 0.f};

    int cur = 0;
    for (int step = 0; step < 32; ++step) {
      *reinterpret_cast<us8*>(&sA[cur * 5120 + aOff]) = aReg;
#pragma unroll
      for (int p = 0; p < 2; p++) *reinterpret_cast<us8*>(&sB[cur * 10240 + bOff[p]]) = bReg[p];
      if (step < 31) {
        int k0 = (step + 1) * 32;
        aReg = *reinterpret_cast<const us8*>(aSrc + k0);
#pragma unroll
        for (int p = 0; p < 2; p++) bReg[p] = *reinterpret_cast<const us8*>(bSrc[p] + k0);
      }
      pipe_barrier();
      int ka = (lane >> 4) * 8;
      bf16x8 a[4];
#pragma unroll
      for (int mf = 0; mf < 4; mf++)
        a[mf] = *reinterpret_cast<const bf16x8*>(&sA[cur * 5120 + (wm * 64 + mf * 16 + (lane & 15)) * 40 + ka]);
#pragma unroll
      for (int nf = 0; nf < 4; nf++) {
        bf16x8 bb = *reinterpret_cast<const bf16x8*>(&sB[cur * 10240 + (wn * 64 + nf * 16 + (lane & 15)) * 40 + ka]);
#pragma unroll
        for (int mf = 0; mf < 4; mf++)
          acc[mf][nf] = __builtin_amdgcn_mfma_f32_16x16x32_bf16(a[mf], bb, acc[mf][nf], 0, 0, 0);
      }
      cur ^= 1;
    }
#pragma unroll
    for (int mf = 0; mf < 4; mf++) {
#pragma unroll
      for (int t = 0; t < 2; t++) {
#pragma unroll
        for (int r = 0; r < 4; r++) {
          int tok = mt * 128 + wm * 64 + mf * 16 + ((lane >> 4) << 2) + r;
          float g = acc[mf][2 * t][r], u = acc[mf][2 * t + 1][r];
          float hval = (g / (1.f + __expf(-g))) * u;
          int h = ht * 128 + (wn * 2 + t) * 16 + (lane & 15);
          hs[(size_t)(tok * NSH + s) * HSH + h] = f2bf(hval);
        }
      }
    }
    return;
  }

  // ---------- routed_gu path (r14-identical inner loop) ----------
  int idx = b - 256;
  int widx = idx >> 2, ht = idx & 3;
  if (widx >= nwk2[0]) return;
  int item = wk2[widx];
  int e = item & 255, mt = item >> 8;
  int ne = cnt[e * CNTS];
  unsigned short* sA = sPool;                 // [2][128*40]
  unsigned short* sB = sPool + 2 * 128 * 40;  // [2][128*40]
  if (tid < 128) {
    int pos = mt * 128 + tid;
    int p2 = min(pos, ne - 1);
    sTok[tid] = ent[e * N_TOK + p2];
    sW[tid] = (pos < ne) ? wgt[e * N_TOK + p2] : 0.f;
  }
  __syncthreads();

  int ar = tid >> 2, akc = tid & 3;
  const unsigned short* aSrc = xb + (size_t)(sTok[ar] >> 2) * DDIM + akc * 8;
  int aOff = ar * 40 + akc * 8;
  int br = tid >> 2, bkc = tid & 3;
  int sel = (br >> 4) & 1;
  int h = ht * 64 + ((br >> 5) << 4) + (br & 15);
  const unsigned short* bSrc = (sel ? Wub : Wgb) + (size_t)(e * HDIM + h) * DDIM + bkc * 8;
  int bOff = br * 40 + bkc * 8;

  us8 aReg = *reinterpret_cast<const us8*>(aSrc);
  us8 bReg = *reinterpret_cast<const us8*>(bSrc);

  f32x4 acc[4][2];
#pragma unroll
  for (int mf = 0; mf < 4; mf++)
#pragma unroll
    for (int nf = 0; nf < 2; nf++) acc[mf][nf] = {0.f, 0.f, 0.f, 0.f};

  int cur = 0;
  for (int step = 0; step < 32; ++step) {
    *reinterpret_cast<us8*>(&sA[cur * 5120 + aOff]) = aReg;
    *reinterpret_cast<us8*>(&sB[cur * 5120 + bOff]) = bReg;
    if (step < 31) {
      int k0 = (step + 1) * 32;
      aReg = *reinterpret_cast<const us8*>(aSrc + k0);
      bReg = *reinterpret_cast<const us8*>(bSrc + k0);
    }
    pipe_barrier();
    int ka = (lane >> 4) * 8;
    bf16x8 a[4];
#pragma unroll
    for (int mf = 0; mf < 4; mf++)
      a[mf] = *reinterpret_cast<const bf16x8*>(&sA[cur * 5120 + (wm * 64 + mf * 16 + (lane & 15)) * 40 + ka]);
#pragma unroll
    for (int nf = 0; nf < 2; nf++) {
      bf16x8 bb = *reinterpret_cast<const bf16x8*>(&sB[cur * 5120 + (wn * 32 + nf * 16 + (lane & 15)) * 40 + ka]);
#pragma unroll
      for (int mf = 0; mf < 4; mf++)
        acc[mf][nf] = __builtin_amdgcn_mfma_f32_16x16x32_bf16(a[mf], bb, acc[mf][nf], 0, 0, 0);
    }
    cur ^= 1;
  }
#pragma unroll
  for (int mf = 0; mf < 4; mf++) {
#pragma unroll
    for (int r = 0; r < 4; r++) {
      int tl = wm * 64 + mf * 16 + ((lane >> 4) << 2) + r;
      int pos = mt * 128 + tl;
      if (pos < ne) {
        float g = acc[mf][0][r], u = acc[mf][1][r];
        float hval = (g / (1.f + __expf(-g))) * u * sW[tl];
        int ts = sTok[tl];
        int hcol = ht * 64 + wn * 16 + (lane & 15);
        hw[(size_t)ts * HDIM + hcol] = f2bf(hval);
      }
    }
  }
}

// ---------------- fused down-proj: shared (0..255) + routed (256..1023) ----------------
__global__ __launch_bounds__(512) void k_down(const unsigned short* __restrict__ hs,
                                              const unsigned short* __restrict__ Sdb,
                                              const unsigned short* __restrict__ hw,
                                              const unsigned short* __restrict__ Wdb,
                                              const int* __restrict__ cnt,
                                              const int* __restrict__ ent,
                                              unsigned short* __restrict__ Psh,
                                              unsigned short* __restrict__ Pslot,
                                              const int* __restrict__ wk2,
                                              const int* __restrict__ nwk2) {
  __shared__ unsigned short sPool[4 * 128 * 40];  // 40960 B
  __shared__ int sTok[128];
  int tid = threadIdx.x, lane = tid & 63, wid = tid >> 6;
  int wm = wid >> 2, wn = wid & 3;
  int b = blockIdx.x;
  unsigned short* sA = sPool;                 // [2][128*40]
  unsigned short* sB = sPool + 2 * 128 * 40;  // [2][128*40]

  if (b < 256) {
    // ---------- shared_down path (r14-identical) ----------
    int xg = b & 15, mt = b >> 4;
    int dh = xg >> 1, s = xg & 1;

    int ar = tid >> 2, akc = tid & 3;
    const unsigned short* aSrc = hs + (size_t)((mt * 128 + ar) * NSH + s) * HSH + akc * 8;
    int aOff = ar * 40 + akc * 8;
    int br = tid >> 2, bkc = tid & 3;
    const unsigned short* bSrc = Sdb + (size_t)(s * DDIM + dh * 128 + br) * HSH + bkc * 8;
    int bOff = br * 40 + bkc * 8;

    us8 aReg = *reinterpret_cast<const us8*>(aSrc);
    us8 bReg = *reinterpret_cast<const us8*>(bSrc);

    f32x4 acc[4][2];
#pragma unroll
    for (int mf = 0; mf < 4; mf++)
#pragma unroll
      for (int nf = 0; nf < 2; nf++) acc[mf][nf] = {0.f, 0.f, 0.f, 0.f};

    int cur = 0;
    for (int step = 0; step < 32; ++step) {
      *reinterpret_cast<us8*>(&sA[cur * 5120 + aOff]) = aReg;
      *reinterpret_cast<us8*>(&sB[cur * 5120 + bOff]) = bReg;
      if (step < 31) {
        int k0 = (step + 1) * 32;
        aReg = *reinterpret_cast<const us8*>(aSrc + k0);
        bReg = *reinterpret_cast<const us8*>(bSrc + k0);
      }
      pipe_barrier();
      int ka = (lane >> 4) * 8;
      bf16x8 a[4];
#pragma unroll
      for (int mf = 0; mf < 4; mf++)
        a[mf] = *reinterpret_cast<const bf16x8*>(&sA[cur * 5120 + (wm * 64 + mf * 16 + (lane & 15)) * 40 + ka]);
#pragma unroll
      for (int nf = 0; nf < 2; nf++) {
        bf16x8 bb = *reinterpret_cast<const bf16x8*>(&sB[cur * 5120 + (wn * 32 + nf * 16 + (lane & 15)) * 40 + ka]);
#pragma unroll
        for (int mf = 0; mf < 4; mf++)
          acc[mf][nf] = __builtin_amdgcn_mfma_f32_16x16x32_bf16(a[mf], bb, acc[mf][nf], 0, 0, 0);
      }
      cur ^= 1;
    }
#pragma unroll
    for (int mf = 0; mf < 4; mf++) {
#pragma unroll
      for (int nf = 0; nf < 2; nf++) {
#pragma unroll
        for (int r = 0; r < 4; r++) {
          int tok = mt * 128 + wm * 64 + mf * 16 + ((lane >> 4) << 2) + r;
          int d = dh * 128 + wn * 32 + nf * 16 + (lane & 15);
          Psh[(size_t)s * N_TOK * DDIM + (size_t)tok * DDIM + d] = f2bf(acc[mf][nf][r]);
        }
      }
    }
    return;
  }

  // ---------- routed_down path (r14-identical) ----------
  int idx = b - 256;
  int widx = idx >> 3, dh = idx & 7;
  if (widx >= nwk2[0]) return;
  int item = wk2[widx];
  int e = item & 255, mt = item >> 8;
  int ne = cnt[e * CNTS];
  if (tid < 128) {
    int pos = mt * 128 + tid;
    int p2 = min(pos, ne - 1);
    sTok[tid] = ent[e * N_TOK + p2];
  }
  __syncthreads();

  int ar = tid >> 2, akc = tid & 3;
  const unsigned short* aSrc = hw + (size_t)sTok[ar] * HDIM + akc * 8;
  int aOff = ar * 40 + akc * 8;
  int br = tid >> 2, bkc = tid & 3;
  int d0 = dh * 128 + br;
  const unsigned short* bSrc = Wdb + (size_t)(e * DDIM + d0) * HDIM + bkc * 8;
  int bOff = br * 40 + bkc * 8;

  us8 aReg = *reinterpret_cast<const us8*>(aSrc);
  us8 bReg = *reinterpret_cast<const us8*>(bSrc);

  f32x4 acc[4][2];
#pragma unroll
  for (int mf = 0; mf < 4; mf++)
#pragma unroll
    for (int nf = 0; nf < 2; nf++) acc[mf][nf] = {0.f, 0.f, 0.f, 0.f};

  int cur = 0;
  for (int step = 0; step < 8; ++step) {
    *reinterpret_cast<us8*>(&sA[cur * 5120 + aOff]) = aReg;
    *reinterpret_cast<us8*>(&sB[cur * 5120 + bOff]) = bReg;
    if (step < 7) {
      int k0 = (step + 1) * 32;
      aReg = *reinterpret_cast<const us8*>(aSrc + k0);
      bReg = *reinterpret_cast<const us8*>(bSrc + k0);
    }
    pipe_barrier();
    int ka = (lane >> 4) * 8;
    bf16x8 a[4];
#pragma unroll
    for (int mf = 0; mf < 4; mf++)
      a[mf] = *reinterpret_cast<const bf16x8*>(&sA[cur * 5120 + (wm * 64 + mf * 16 + (lane & 15)) * 40 + ka]);
#pragma unroll
    for (int nf = 0; nf < 2; nf++) {
      bf16x8 bb = *reinterpret_cast<const bf16x8*>(&sB[cur * 5120 + (wn * 32 + nf * 16 + (lane & 15)) * 40 + ka]);
#pragma unroll
      for (int mf = 0; mf < 4; mf++)
        acc[mf][nf] = __builtin_amdgcn_mfma_f32_16x16x32_bf16(a[mf], bb, acc[mf][nf], 0, 0, 0);
    }
    cur ^= 1;
  }
#pragma unroll
  for (int mf = 0; mf < 4; mf++) {
#pragma unroll
    for (int nf = 0; nf < 2; nf++) {
#pragma unroll
      for (int r = 0; r < 4; r++) {
        int tl = wm * 64 + mf * 16 + ((lane >> 4) << 2) + r;
        int pos = mt * 128 + tl;
        if (pos < ne) {
          int ts = sTok[tl];
          int d = dh * 128 + wn * 32 + nf * 16 + (lane & 15);
          Pslot[(size_t)ts * DDIM + d] = f2bf(acc[mf][nf][r]);
        }
      }
    }
  }
}

// ---------------- final combine ----------------
__global__ __launch_bounds__(256) void k_combine(const unsigned short* __restrict__ Pslot,
                                                 const unsigned short* __restrict__ Psh,
                                                 float* __restrict__ out) {
  int i = blockIdx.x * 256 + threadIdx.x;
  int base = i * 8;
  int tok = base >> 10, d = base & 1023;
  const us8 p0 = *reinterpret_cast<const us8*>(Pslot + ((size_t)tok * 4 + 0) * DDIM + d);
  const us8 p1 = *reinterpret_cast<const us8*>(Pslot + ((size_t)tok * 4 + 1) * DDIM + d);
  const us8 p2 = *reinterpret_cast<const us8*>(Pslot + ((size_t)tok * 4 + 2) * DDIM + d);
  const us8 p3 = *reinterpret_cast<const us8*>(Pslot + ((size_t)tok * 4 + 3) * DDIM + d);
  const us8 q0 = *reinterpret_cast<const us8*>(Psh + (size_t)base);
  const us8 q1 = *reinterpret_cast<const us8*>(Psh + (size_t)N_TOK * DDIM + base);
  float o[8];
#pragma unroll
  for (int j = 0; j < 8; j++)
    o[j] = bf2f(p0[j]) + bf2f(p1[j]) + bf2f(p2[j]) + bf2f(p3[j]) + bf2f(q0[j]) + bf2f(q1[j]);
  float4 v0 = {o[0], o[1], o[2], o[3]};
  float4 v1 = {o[4], o[5], o[6], o[7]};
  reinterpret_cast<float4*>(out + base)[0] = v0;
  reinterpret_cast<float4*>(out + base)[1] = v1;
}

extern "C" void kernel_launch(void* const* d_in, const int* in_sizes, int n_in,
                              void* d_out, int out_size, void* d_ws, size_t ws_size,
                              hipStream_t stream) {
  const float* x  = (const float*)d_in[0];
  const float* Wr = (const float*)d_in[1];
  const float* rb = (const float*)d_in[2];
  const float* Wg = (const float*)d_in[3];
  const float* Wu = (const float*)d_in[4];
  const float* Wd = (const float*)d_in[5];
  const float* Sg = (const float*)d_in[6];
  const float* Su = (const float*)d_in[7];
  const float* Sd = (const float*)d_in[8];
  float* out = (float*)d_out;
  char* w = (char*)d_ws;

  unsigned short* xb    = (unsigned short*)(w + (size_t)0);            // 4MB
  unsigned short* Wgb   = (unsigned short*)(w + ((size_t)4  << 20));   // 16MB
  unsigned short* Wub   = (unsigned short*)(w + ((size_t)20 << 20));   // 16MB
  unsigned short* Wdb   = (unsigned short*)(w + ((size_t)36 << 20));   // 16MB
  unsigned short* Sgb   = (unsigned short*)(w + ((size_t)52 << 20));   // 4MB
  unsigned short* Sub   = (unsigned short*)(w + ((size_t)56 << 20));   // 4MB
  unsigned short* Sdb   = (unsigned short*)(w + ((size_t)60 << 20));   // 4MB
  unsigned short* hw    = (unsigned short*)(w + ((size_t)64 << 20));   // 4MB
  unsigned short* hs    = (unsigned short*)(w + ((size_t)68 << 20));   // 8MB
  unsigned short* Pslot = (unsigned short*)(w + ((size_t)76 << 20));   // 16MB
  unsigned short* Psh   = (unsigned short*)(w + ((size_t)92 << 20));   // 8MB
  int*   cnt = (int*)(w + ((size_t)100 << 20));
  int*   ent = (int*)(w + ((size_t)100 << 20) + 8192);
  float* wgt = (float*)(w + ((size_t)100 << 20) + 8192 + (size_t)NEXP * N_TOK * 4);
  int*   wk2  = (int*)(w + ((size_t)102 << 20));
  int*   nwk2 = (int*)(w + ((size_t)102 << 20) + 4096);

  hipMemsetAsync(cnt, 0, NEXP * CNTS * sizeof(int), stream);

  k_prep<<<256 + NCVT, 256, 0, stream>>>(x, Wr, rb, Wg, Wu, Wd, Sg, Su, Sd,
                                         xb, Wgb, Wub, Wdb, Sgb, Sub, Sdb,
                                         cnt, ent, wgt);
  k_plan<<<1, 64, 0, stream>>>(cnt, wk2, nwk2);

  k_gu<<<256 + WM2 * 4, 512, 0, stream>>>(xb, Sgb, Sub, Wgb, Wub, cnt, ent, wgt,
                                          hs, hw, wk2, nwk2);
  k_down<<<256 + WM2 * 8, 512, 0, stream>>>(hs, Sdb, hw, Wdb, cnt, ent,
                                            Psh, Pslot, wk2, nwk2);

  k_combine<<<N_TOK * DDIM / (256 * 8), 256, 0, stream>>>(Pslot, Psh, out);
}